// Round 2
// baseline (692.406 us; speedup 1.0000x reference)
//
#include <hip/hip_runtime.h>

#define NN 50000
#define NE 800000
#define ET 850000   // NE + NN self-loops
#define NG 64
#define D  128

// ---------------- CSR build ----------------
__global__ void k_init(int* cnt, int* cur, float* bsum, float* bsq){
  int i = blockIdx.x*256 + threadIdx.x;
  if (i < NN){ cnt[i] = 1; cur[i] = 0; }   // 1 = self-loop
  if (i < 128){ bsum[i] = 0.f; bsq[i] = 0.f; }
}

__global__ void k_hist(const int* __restrict__ dstE, int* __restrict__ cnt){
  int e = blockIdx.x*256 + threadIdx.x;
  if (e < NE) atomicAdd(&cnt[dstE[e]], 1);
}

__global__ void k_scan_a(const int* __restrict__ cnt, int* __restrict__ offs, int* __restrict__ bsums){
  __shared__ int s[256];
  int tid = threadIdx.x;
  int i = blockIdx.x*256 + tid;
  int v = (i < NN) ? cnt[i] : 0;
  s[tid] = v;
  __syncthreads();
  for (int off = 1; off < 256; off <<= 1){
    int t = (tid >= off) ? s[tid-off] : 0;
    __syncthreads();
    s[tid] += t;
    __syncthreads();
  }
  if (i < NN) offs[i] = s[tid] - v;          // exclusive within block
  if (tid == 255) bsums[blockIdx.x] = s[255];
}

__global__ void k_scan_b(const int* __restrict__ bsums, int* __restrict__ bbase){
  __shared__ int s[256];
  int tid = threadIdx.x;
  int v = (tid < 196) ? bsums[tid] : 0;
  s[tid] = v;
  __syncthreads();
  for (int off = 1; off < 256; off <<= 1){
    int t = (tid >= off) ? s[tid-off] : 0;
    __syncthreads();
    s[tid] += t;
    __syncthreads();
  }
  if (tid < 196) bbase[tid] = s[tid] - v;
}

__global__ void k_scan_c(int* __restrict__ offs, const int* __restrict__ bbase){
  int i = blockIdx.x*256 + threadIdx.x;
  if (i < NN) offs[i] += bbase[blockIdx.x];
  if (i == 0) offs[NN] = ET;
}

__global__ void k_scatter(const int* __restrict__ srcE, const int* __restrict__ dstE,
                          const int* __restrict__ offs, int* __restrict__ cur,
                          int* __restrict__ srcs){
  int i = blockIdx.x*256 + threadIdx.x;
  if (i >= ET) return;
  int s, d;
  if (i < NE){ s = srcE[i]; d = dstE[i]; } else { s = i - NE; d = s; }
  int pos = offs[d] + atomicAdd(&cur[d], 1);
  srcs[pos] = s;
}

// ---------------- GEMM: Y[n,128] = X[n,128] @ W[128,128], f32 ----------------
#define ACC4(aX, wX) { aX.x = fmaf(xv, wX.x, aX.x); aX.y = fmaf(xv, wX.y, aX.y); \
                       aX.z = fmaf(xv, wX.z, aX.z); aX.w = fmaf(xv, wX.w, aX.w); }

__global__ __launch_bounds__(256) void k_gemm(const float* __restrict__ X, const float* __restrict__ W,
                                              float* __restrict__ Y, int nrows){
  __shared__ float Wl[D*D];      // 64 KB
  __shared__ float xs[32*132];   // 16.9 KB
  int tid = threadIdx.x;
  {
    const float4* wg = (const float4*)W;
    float4* wl = (float4*)Wl;
    for (int i = tid; i < 4096; i += 256) wl[i] = wg[i];
  }
  int row0 = blockIdx.x * 32;
  for (int i = tid; i < 4096; i += 256){
    int r = i >> 7, c = i & 127;
    int gr = row0 + r;
    xs[r*132 + c] = (gr < nrows) ? X[gr*D + c] : 0.f;
  }
  __syncthreads();
  int r = tid >> 3, cg = tid & 7;
  float4 a0 = {0,0,0,0}, a1 = a0, a2 = a0, a3 = a0;
  const float4* wl4 = (const float4*)Wl;
  #pragma unroll 4
  for (int k = 0; k < D; k++){
    float xv = xs[r*132 + k];
    float4 w0 = wl4[k*32 + cg];
    float4 w1 = wl4[k*32 + cg + 8];
    float4 w2 = wl4[k*32 + cg + 16];
    float4 w3 = wl4[k*32 + cg + 24];
    ACC4(a0, w0); ACC4(a1, w1); ACC4(a2, w2); ACC4(a3, w3);
  }
  int gr = row0 + r;
  if (gr < nrows){
    float4* yr = (float4*)(Y + gr*D);
    yr[cg]      = a0;
    yr[cg + 8]  = a1;
    yr[cg + 16] = a2;
    yr[cg + 24] = a3;
  }
}

// ---------------- attention coefficients: a[n,h] = sum_c h[n,h*32+c]*att[h,c] ----------------
__global__ void k_att(const float* __restrict__ h, const float* __restrict__ att_s,
                      const float* __restrict__ att_d, float* __restrict__ asrc,
                      float* __restrict__ adst){
  int tid = threadIdx.x;
  int c = tid & 127;
  int n = blockIdx.x*2 + (tid >> 7);
  float hv = h[n*D + c];
  float ps = hv * att_s[c];
  float pd = hv * att_d[c];
  #pragma unroll
  for (int m = 1; m <= 16; m <<= 1){
    ps += __shfl_xor(ps, m);
    pd += __shfl_xor(pd, m);
  }
  if ((tid & 31) == 0){
    int head = c >> 5;
    asrc[n*4 + head] = ps;
    adst[n*4 + head] = pd;
  }
}

// ---------------- GAT edge softmax + aggregate: one wave per destination node ----------------
__global__ void k_edge(const float* __restrict__ h, const float* __restrict__ asrc,
                       const float* __restrict__ adst, const int* __restrict__ offs,
                       const int* __restrict__ srcs, const float* __restrict__ bias,
                       float* __restrict__ out){
  int lane = threadIdx.x & 63;
  int n = blockIdx.x*4 + (threadIdx.x >> 6);
  int off0 = offs[n];
  int deg  = offs[n+1] - off0;
  int hq = lane & 3;                       // head for phases 1-2
  float adn = adst[n*4 + hq];
  // phase 1: per-head max over incoming edges
  float m = -1e30f;
  for (int i = lane >> 2; i < deg; i += 16){
    int s = srcs[off0 + i];
    float e = asrc[s*4 + hq] + adn;
    e = e > 0.f ? e : 0.2f*e;
    m = fmaxf(m, e);
  }
  #pragma unroll
  for (int msk = 4; msk < 64; msk <<= 1) m = fmaxf(m, __shfl_xor(m, msk));
  // phase 2: per-head denom
  float sm = 0.f;
  for (int i = lane >> 2; i < deg; i += 16){
    int s = srcs[off0 + i];
    float e = asrc[s*4 + hq] + adn;
    e = e > 0.f ? e : 0.2f*e;
    sm += expf(e - m);
  }
  #pragma unroll
  for (int msk = 4; msk < 64; msk <<= 1) sm += __shfl_xor(sm, msk);
  // phase 3: aggregate; lane owns channels 2*lane, 2*lane+1 (head = lane>>4)
  int hd = lane >> 4;
  float mh  = __shfl(m, hd);
  float inv = 1.f / __shfl(sm, hd);
  float adh = __shfl(adn, hd);
  float2 acc = {0.f, 0.f};
  for (int i = 0; i < deg; i++){
    int s = srcs[off0 + i];
    float e = asrc[s*4 + hd] + adh;
    e = e > 0.f ? e : 0.2f*e;
    float al = expf(e - mh) * inv;
    float2 hv = ((const float2*)(h + s*D))[lane];
    acc.x = fmaf(al, hv.x, acc.x);
    acc.y = fmaf(al, hv.y, acc.y);
  }
  int c = lane*2;
  float2 o;
  o.x = acc.x + bias[c];
  o.y = acc.y + bias[c+1];
  ((float2*)(out + n*D))[lane] = o;
}

// ---------------- BatchNorm ----------------
__global__ void k_bnstat(const float* __restrict__ B, float* __restrict__ bsum, float* __restrict__ bsq){
  int tid = threadIdx.x;
  int c = tid & 127;
  int r0 = blockIdx.x*2 + (tid >> 7);
  float s = 0.f, q = 0.f;
  for (int r = r0; r < NN; r += 512){
    float v = B[r*D + c];
    s += v; q += v*v;
  }
  atomicAdd(&bsum[c], s);
  atomicAdd(&bsq[c], q);
}

__global__ void k_bnfin(const float* __restrict__ bsum, const float* __restrict__ bsq,
                        const float* __restrict__ gamma, const float* __restrict__ beta,
                        float* __restrict__ scale, float* __restrict__ shift){
  int c = threadIdx.x;  // 128
  float mu  = bsum[c] * (1.f/NN);
  float var = bsq[c] * (1.f/NN) - mu*mu;
  float sc  = gamma[c] * rsqrtf(var + 1e-5f);
  scale[c] = sc;
  shift[c] = beta[c] - mu*sc;
}

__global__ void k_bnapply(float* __restrict__ B, const float* __restrict__ scale,
                          const float* __restrict__ shift){
  int i = blockIdx.x*256 + threadIdx.x;     // over float4s
  if (i >= NN*D/4) return;
  float4 v = ((float4*)B)[i];
  int cb = i & 31;
  float4 sc = ((const float4*)scale)[cb];
  float4 sh = ((const float4*)shift)[cb];
  v.x = fmaf(v.x, sc.x, sh.x); v.y = fmaf(v.y, sc.y, sh.y);
  v.z = fmaf(v.z, sc.z, sh.z); v.w = fmaf(v.w, sc.w, sh.w);
  v.x = v.x > 0.f ? v.x : expm1f(v.x);
  v.y = v.y > 0.f ? v.y : expm1f(v.y);
  v.z = v.z > 0.f ? v.z : expm1f(v.z);
  v.w = v.w > 0.f ? v.w : expm1f(v.w);
  ((float4*)B)[i] = v;
}

// ---------------- global mean pool (batch is sorted) ----------------
__global__ void k_pool(const float* __restrict__ h2, const int* __restrict__ batch,
                       float* __restrict__ out){
  __shared__ float red[256];
  int g = blockIdx.x;
  int tid = threadIdx.x;
  int c = tid & 127, half = tid >> 7;
  int lo = 0, hi = NN;
  while (lo < hi){ int mid = (lo+hi) >> 1; if (batch[mid] < g) lo = mid+1; else hi = mid; }
  int a = lo, b = NN;
  while (a < b){ int mid = (a+b) >> 1; if (batch[mid] < g+1) a = mid+1; else b = mid; }
  int cntg = a - lo;
  float s = 0.f;
  for (int r = lo + half; r < a; r += 2) s += h2[r*D + c];
  red[tid] = s;
  __syncthreads();
  if (tid < 128){
    float tot = red[tid] + red[tid + 128];
    out[g*D + tid] = tot / (float)(cntg > 1 ? cntg : 1);
  }
}

extern "C" void kernel_launch(void* const* d_in, const int* in_sizes, int n_in,
                              void* d_out, int out_size, void* d_ws, size_t ws_size,
                              hipStream_t stream){
  (void)in_sizes; (void)n_in; (void)out_size; (void)ws_size;
  const float* x   = (const float*)d_in[0];
  const int* ei    = (const int*)d_in[1];
  const int* batch = (const int*)d_in[2];
  const float* W1  = (const float*)d_in[3];
  const float* as1 = (const float*)d_in[4];
  const float* ad1 = (const float*)d_in[5];
  const float* b1  = (const float*)d_in[6];
  const float* g1  = (const float*)d_in[7];
  const float* be1 = (const float*)d_in[8];
  const float* W2  = (const float*)d_in[9];
  const float* as2 = (const float*)d_in[10];
  const float* ad2 = (const float*)d_in[11];
  const float* b2  = (const float*)d_in[12];
  float* outp = (float*)d_out;

  float* A    = (float*)d_ws;          // 6.4M f32 (linear transform output)
  float* B    = A + 6400000;           // 6.4M f32 (aggregated / BN / ELU)
  float* asr  = B + 6400000;           // 200K
  float* ads  = asr + 200000;          // 200K
  float* bsum = ads + 200000;          // 128
  float* bsq  = bsum + 128;            // 128
  float* bsc  = bsq + 128;             // 128
  float* bsh  = bsc + 128;             // 128
  int* cnt    = (int*)(bsh + 128);     // 50000
  int* cur    = cnt + NN;              // 50000
  int* offs   = cur + NN;              // 50001
  int* srcs   = offs + (NN+1);         // 850000
  int* bsums  = srcs + ET;             // 256
  int* bbase  = bsums + 256;           // 256

  const int* srcE = ei;
  const int* dstE = ei + NE;

  // CSR by destination (self-loops included), rebuilt every call (deterministic work)
  k_init<<<196, 256, 0, stream>>>(cnt, cur, bsum, bsq);
  k_hist<<<(NE+255)/256, 256, 0, stream>>>(dstE, cnt);
  k_scan_a<<<196, 256, 0, stream>>>(cnt, offs, bsums);
  k_scan_b<<<1, 256, 0, stream>>>(bsums, bbase);
  k_scan_c<<<196, 256, 0, stream>>>(offs, bbase);
  k_scatter<<<(ET+255)/256, 256, 0, stream>>>(srcE, dstE, offs, cur, srcs);

  // layer 1
  k_gemm<<<1563, 256, 0, stream>>>(x, W1, A, NN);
  k_att<<<NN/2, 256, 0, stream>>>(A, as1, ad1, asr, ads);
  k_edge<<<NN/4, 256, 0, stream>>>(A, asr, ads, offs, srcs, b1, B);
  // BN + ELU
  k_bnstat<<<256, 256, 0, stream>>>(B, bsum, bsq);
  k_bnfin<<<1, 128, 0, stream>>>(bsum, bsq, g1, be1, bsc, bsh);
  k_bnapply<<<(NN*D/4+255)/256, 256, 0, stream>>>(B, bsc, bsh);
  // layer 2
  k_gemm<<<1563, 256, 0, stream>>>(B, W2, A, NN);
  k_att<<<NN/2, 256, 0, stream>>>(A, as2, ad2, asr, ads);
  k_edge<<<NN/4, 256, 0, stream>>>(A, asr, ads, offs, srcs, b2, outp);
  // pool
  k_pool<<<NG, 256, 0, stream>>>(outp, batch, outp + 6400000);
}

// Round 3
// 442.497 us; speedup vs baseline: 1.5648x; 1.5648x over previous
//
#include <hip/hip_runtime.h>

#define NN 50000
#define NE 800000
#define ET 850000   // NE + NN self-loops
#define NG 64
#define D  128

// ---------------- CSR build ----------------
__global__ void k_init(int* cnt, int* cur, float* bsum, float* bsq, float* pooled){
  int i = blockIdx.x*256 + threadIdx.x;
  if (i < NN){ cnt[i] = 1; cur[i] = 0; }   // 1 = self-loop
  if (i < 128){ bsum[i] = 0.f; bsq[i] = 0.f; }
  if (i < NG*D) pooled[i] = 0.f;
}

__global__ void k_hist(const int* __restrict__ dstE, int* __restrict__ cnt){
  int e = blockIdx.x*256 + threadIdx.x;
  if (e < NE) atomicAdd(&cnt[dstE[e]], 1);
}

__global__ void k_scan_a(const int* __restrict__ cnt, int* __restrict__ offs, int* __restrict__ bsums){
  __shared__ int s[256];
  int tid = threadIdx.x;
  int i = blockIdx.x*256 + tid;
  int v = (i < NN) ? cnt[i] : 0;
  s[tid] = v;
  __syncthreads();
  for (int off = 1; off < 256; off <<= 1){
    int t = (tid >= off) ? s[tid-off] : 0;
    __syncthreads();
    s[tid] += t;
    __syncthreads();
  }
  if (i < NN) offs[i] = s[tid] - v;          // exclusive within block
  if (tid == 255) bsums[blockIdx.x] = s[255];
}

__global__ void k_scan_b(const int* __restrict__ bsums, int* __restrict__ bbase){
  __shared__ int s[256];
  int tid = threadIdx.x;
  int v = (tid < 196) ? bsums[tid] : 0;
  s[tid] = v;
  __syncthreads();
  for (int off = 1; off < 256; off <<= 1){
    int t = (tid >= off) ? s[tid-off] : 0;
    __syncthreads();
    s[tid] += t;
    __syncthreads();
  }
  if (tid < 196) bbase[tid] = s[tid] - v;
}

__global__ void k_scan_c(int* __restrict__ offs, const int* __restrict__ bbase){
  int i = blockIdx.x*256 + threadIdx.x;
  if (i < NN) offs[i] += bbase[blockIdx.x];
  if (i == 0) offs[NN] = ET;
}

__global__ void k_scatter(const int* __restrict__ srcE, const int* __restrict__ dstE,
                          const int* __restrict__ offs, int* __restrict__ cur,
                          int* __restrict__ srcs){
  int i = blockIdx.x*256 + threadIdx.x;
  if (i >= ET) return;
  int s, d;
  if (i < NE){ s = srcE[i]; d = dstE[i]; } else { s = i - NE; d = s; }
  int pos = offs[d] + atomicAdd(&cur[d], 1);
  srcs[pos] = s;
}

// ---------------- GEMM: Y[n,128] = X[n,128] @ W[128,128], f32 ----------------
#define ACC4(aX, wX) { aX.x = fmaf(xv, wX.x, aX.x); aX.y = fmaf(xv, wX.y, aX.y); \
                       aX.z = fmaf(xv, wX.z, aX.z); aX.w = fmaf(xv, wX.w, aX.w); }

__global__ __launch_bounds__(512) void k_gemm(const float* __restrict__ X, const float* __restrict__ W,
                                              float* __restrict__ Y, int nrows){
  __shared__ float Wl[D*D];      // 64 KB
  __shared__ float xs[64*132];   // 33.8 KB
  int tid = threadIdx.x;
  {
    const float4* wg = (const float4*)W;
    float4* wl = (float4*)Wl;
    for (int i = tid; i < 4096; i += 512) wl[i] = wg[i];
  }
  int row0 = blockIdx.x * 64;
  for (int i = tid; i < 8192; i += 512){
    int r = i >> 7, c = i & 127;
    int gr = row0 + r;
    xs[r*132 + c] = (gr < nrows) ? X[gr*D + c] : 0.f;
  }
  __syncthreads();
  int r = tid >> 3, cg = tid & 7;
  float4 a0 = {0,0,0,0}, a1 = a0, a2 = a0, a3 = a0;
  const float4* wl4 = (const float4*)Wl;
  #pragma unroll 4
  for (int k = 0; k < D; k++){
    float xv = xs[r*132 + k];
    float4 w0 = wl4[k*32 + cg];
    float4 w1 = wl4[k*32 + cg + 8];
    float4 w2 = wl4[k*32 + cg + 16];
    float4 w3 = wl4[k*32 + cg + 24];
    ACC4(a0, w0); ACC4(a1, w1); ACC4(a2, w2); ACC4(a3, w3);
  }
  int gr = row0 + r;
  if (gr < nrows){
    float4* yr = (float4*)(Y + gr*D);
    yr[cg]      = a0;
    yr[cg + 8]  = a1;
    yr[cg + 16] = a2;
    yr[cg + 24] = a3;
  }
}

// ---------------- attention coefficients: a[n,h] = sum_c h[n,h*32+c]*att[h,c] ----------------
__global__ void k_att(const float* __restrict__ h, const float* __restrict__ att_s,
                      const float* __restrict__ att_d, float* __restrict__ asrc,
                      float* __restrict__ adst){
  int tid = threadIdx.x;
  int c = tid & 127;
  int n = blockIdx.x*2 + (tid >> 7);
  float hv = h[n*D + c];
  float ps = hv * att_s[c];
  float pd = hv * att_d[c];
  #pragma unroll
  for (int m = 1; m <= 16; m <<= 1){
    ps += __shfl_xor(ps, m);
    pd += __shfl_xor(pd, m);
  }
  if ((tid & 31) == 0){
    int head = c >> 5;
    asrc[n*4 + head] = ps;
    adst[n*4 + head] = pd;
  }
}

// ---------------- GAT edge softmax + aggregate: one wave per destination node ----------------
__global__ __launch_bounds__(256) void k_edge(
                       const float* __restrict__ h, const float* __restrict__ asrc,
                       const float* __restrict__ adst, const int* __restrict__ offs,
                       const int* __restrict__ srcs, const float* __restrict__ bias,
                       float* __restrict__ out){
  __shared__ int   sSrc[4][16];
  __shared__ float sAl[4][4][16];
  int w = threadIdx.x >> 6;
  int lane = threadIdx.x & 63;
  int n = blockIdx.x*4 + w;
  int off0 = offs[n];
  int deg  = offs[n+1] - off0;
  int hq = lane & 3;                       // head for phases 1-2
  float adn = adst[n*4 + hq];
  // phase 1: per-head max over incoming edges (16-way per head)
  float m = -1e30f;
  for (int i = lane >> 2; i < deg; i += 16){
    int s = srcs[off0 + i];
    float e = asrc[s*4 + hq] + adn;
    e = e > 0.f ? e : 0.2f*e;
    m = fmaxf(m, e);
  }
  #pragma unroll
  for (int msk = 4; msk < 64; msk <<= 1) m = fmaxf(m, __shfl_xor(m, msk));
  // phase 2: per-head denom
  float sm = 0.f;
  for (int i = lane >> 2; i < deg; i += 16){
    int s = srcs[off0 + i];
    float e = asrc[s*4 + hq] + adn;
    e = e > 0.f ? e : 0.2f*e;
    sm += expf(e - m);
  }
  #pragma unroll
  for (int msk = 4; msk < 64; msk <<= 1) sm += __shfl_xor(sm, msk);
  // phase 3: aggregate. lane owns channels 2*lane..2*lane+1, head hd = lane>>4.
  // Edges processed in chunks of 16: all 64 lanes cooperatively compute alpha
  // (lane = hd*16 + j computes alpha of edge j for head hd -> 1 exp/lane/chunk),
  // parked in LDS, then an unrolled gather loop.
  int hd = lane >> 4, j16 = lane & 15;
  float mh  = __shfl(m, hd);
  float inv = 1.f / __shfl(sm, hd);
  float adh = __shfl(adn, hd);
  float2 acc = {0.f, 0.f};
  const float2* h2p = (const float2*)h;
  for (int base = 0; base < deg; base += 16){
    int lim = deg - base; if (lim > 16) lim = 16;
    int sj = 0; float al = 0.f;
    if (j16 < lim){
      sj = srcs[off0 + base + j16];
      float e = asrc[sj*4 + hd] + adh;
      e = e > 0.f ? e : 0.2f*e;
      al = expf(e - mh) * inv;
    }
    sSrc[w][j16] = sj;          // all 4 head groups write identical values
    sAl[w][hd][j16] = al;
    int j = 0;
    for (; j + 4 <= lim; j += 4){
      int s0 = sSrc[w][j],   s1 = sSrc[w][j+1], s2 = sSrc[w][j+2], s3 = sSrc[w][j+3];
      float c0 = sAl[w][hd][j],   c1 = sAl[w][hd][j+1];
      float c2 = sAl[w][hd][j+2], c3 = sAl[w][hd][j+3];
      float2 v0 = h2p[s0*64 + lane];
      float2 v1 = h2p[s1*64 + lane];
      float2 v2 = h2p[s2*64 + lane];
      float2 v3 = h2p[s3*64 + lane];
      acc.x = fmaf(c0, v0.x, acc.x); acc.y = fmaf(c0, v0.y, acc.y);
      acc.x = fmaf(c1, v1.x, acc.x); acc.y = fmaf(c1, v1.y, acc.y);
      acc.x = fmaf(c2, v2.x, acc.x); acc.y = fmaf(c2, v2.y, acc.y);
      acc.x = fmaf(c3, v3.x, acc.x); acc.y = fmaf(c3, v3.y, acc.y);
    }
    for (; j < lim; j++){
      int s0 = sSrc[w][j];
      float c0 = sAl[w][hd][j];
      float2 v0 = h2p[s0*64 + lane];
      acc.x = fmaf(c0, v0.x, acc.x); acc.y = fmaf(c0, v0.y, acc.y);
    }
  }
  int c = lane*2;
  float2 o;
  o.x = acc.x + bias[c];
  o.y = acc.y + bias[c+1];
  ((float2*)(out + n*D))[lane] = o;
}

// ---------------- BatchNorm ----------------
__global__ void k_bnstat(const float* __restrict__ B, float* __restrict__ bsum, float* __restrict__ bsq){
  int tid = threadIdx.x;
  int c = tid & 127;
  int r0 = blockIdx.x*2 + (tid >> 7);
  float s = 0.f, q = 0.f;
  for (int r = r0; r < NN; r += 512){
    float v = B[r*D + c];
    s += v; q += v*v;
  }
  atomicAdd(&bsum[c], s);
  atomicAdd(&bsq[c], q);
}

__global__ void k_bnfin(const float* __restrict__ bsum, const float* __restrict__ bsq,
                        const float* __restrict__ gamma, const float* __restrict__ beta,
                        float* __restrict__ scale, float* __restrict__ shift){
  int c = threadIdx.x;  // 128
  float mu  = bsum[c] * (1.f/NN);
  float var = bsq[c] * (1.f/NN) - mu*mu;
  float sc  = gamma[c] * rsqrtf(var + 1e-5f);
  scale[c] = sc;
  shift[c] = beta[c] - mu*sc;
}

__global__ void k_bnapply(float* __restrict__ B, const float* __restrict__ scale,
                          const float* __restrict__ shift){
  int i = blockIdx.x*256 + threadIdx.x;     // over float4s
  if (i >= NN*D/4) return;
  float4 v = ((float4*)B)[i];
  int cb = i & 31;
  float4 sc = ((const float4*)scale)[cb];
  float4 sh = ((const float4*)shift)[cb];
  v.x = fmaf(v.x, sc.x, sh.x); v.y = fmaf(v.y, sc.y, sh.y);
  v.z = fmaf(v.z, sc.z, sh.z); v.w = fmaf(v.w, sc.w, sh.w);
  v.x = v.x > 0.f ? v.x : expm1f(v.x);
  v.y = v.y > 0.f ? v.y : expm1f(v.y);
  v.z = v.z > 0.f ? v.z : expm1f(v.z);
  v.w = v.w > 0.f ? v.w : expm1f(v.w);
  ((float4*)B)[i] = v;
}

// ---------------- global mean pool (batch sorted): stage A accumulate ----------------
#define POOL_ROWS 50
__global__ void k_poolA(const float* __restrict__ h2, const int* __restrict__ batch,
                        float* __restrict__ pooled){
  int c = threadIdx.x & 127;
  int half = threadIdx.x >> 7;
  int r0 = blockIdx.x * POOL_ROWS;
  int r1 = r0 + POOL_ROWS; if (r1 > NN) r1 = NN;
  float s = 0.f; int g = -1;
  for (int r = r0 + half; r < r1; r += 2){
    int bg = batch[r];
    if (bg != g){
      if (g >= 0) atomicAdd(&pooled[g*D + c], s);
      g = bg; s = 0.f;
    }
    s += h2[r*D + c];
  }
  if (g >= 0) atomicAdd(&pooled[g*D + c], s);
}

// ---------------- stage B: divide by count ----------------
__global__ void k_poolB(const float* __restrict__ pooled, const int* __restrict__ batch,
                        float* __restrict__ out){
  int g = blockIdx.x;
  int c = threadIdx.x;   // 128
  int lo = 0, hi = NN;
  while (lo < hi){ int mid = (lo+hi) >> 1; if (batch[mid] < g) lo = mid+1; else hi = mid; }
  int a = lo, b = NN;
  while (a < b){ int mid = (a+b) >> 1; if (batch[mid] < g+1) a = mid+1; else b = mid; }
  int cntg = a - lo;
  out[g*D + c] = pooled[g*D + c] / (float)(cntg > 1 ? cntg : 1);
}

extern "C" void kernel_launch(void* const* d_in, const int* in_sizes, int n_in,
                              void* d_out, int out_size, void* d_ws, size_t ws_size,
                              hipStream_t stream){
  (void)in_sizes; (void)n_in; (void)out_size; (void)ws_size;
  const float* x   = (const float*)d_in[0];
  const int* ei    = (const int*)d_in[1];
  const int* batch = (const int*)d_in[2];
  const float* W1  = (const float*)d_in[3];
  const float* as1 = (const float*)d_in[4];
  const float* ad1 = (const float*)d_in[5];
  const float* b1  = (const float*)d_in[6];
  const float* g1  = (const float*)d_in[7];
  const float* be1 = (const float*)d_in[8];
  const float* W2  = (const float*)d_in[9];
  const float* as2 = (const float*)d_in[10];
  const float* ad2 = (const float*)d_in[11];
  const float* b2  = (const float*)d_in[12];
  float* outp = (float*)d_out;

  float* A    = (float*)d_ws;          // 6.4M f32
  float* B    = A + 6400000;           // 6.4M f32
  float* asr  = B + 6400000;           // 200K
  float* ads  = asr + 200000;          // 200K
  float* bsum = ads + 200000;          // 128
  float* bsq  = bsum + 128;            // 128
  float* bsc  = bsq + 128;             // 128
  float* bsh  = bsc + 128;             // 128
  int* cnt    = (int*)(bsh + 128);     // 50000
  int* cur    = cnt + NN;              // 50000
  int* offs   = cur + NN;              // 50001
  int* srcs   = offs + (NN+1);         // 850000
  int* bsums  = srcs + ET;             // 256
  int* bbase  = bsums + 256;           // 256
  float* pooled = (float*)(bbase + 256); // 8192

  const int* srcE = ei;
  const int* dstE = ei + NE;

  // CSR by destination (self-loops included), rebuilt every call (deterministic work)
  k_init<<<196, 256, 0, stream>>>(cnt, cur, bsum, bsq, pooled);
  k_hist<<<(NE+255)/256, 256, 0, stream>>>(dstE, cnt);
  k_scan_a<<<196, 256, 0, stream>>>(cnt, offs, bsums);
  k_scan_b<<<1, 256, 0, stream>>>(bsums, bbase);
  k_scan_c<<<196, 256, 0, stream>>>(offs, bbase);
  k_scatter<<<(ET+255)/256, 256, 0, stream>>>(srcE, dstE, offs, cur, srcs);

  // layer 1
  k_gemm<<<782, 512, 0, stream>>>(x, W1, A, NN);
  k_att<<<NN/2, 256, 0, stream>>>(A, as1, ad1, asr, ads);
  k_edge<<<NN/4, 256, 0, stream>>>(A, asr, ads, offs, srcs, b1, B);
  // BN + ELU
  k_bnstat<<<256, 256, 0, stream>>>(B, bsum, bsq);
  k_bnfin<<<1, 128, 0, stream>>>(bsum, bsq, g1, be1, bsc, bsh);
  k_bnapply<<<(NN*D/4+255)/256, 256, 0, stream>>>(B, bsc, bsh);
  // layer 2
  k_gemm<<<782, 512, 0, stream>>>(B, W2, A, NN);
  k_att<<<NN/2, 256, 0, stream>>>(A, as2, ad2, asr, ads);
  k_edge<<<NN/4, 256, 0, stream>>>(A, asr, ads, offs, srcs, b2, outp);
  // pool
  k_poolA<<<(NN + POOL_ROWS - 1)/POOL_ROWS, 256, 0, stream>>>(outp, batch, pooled);
  k_poolB<<<NG, 128, 0, stream>>>(pooled, batch, outp + 6400000);
}

// Round 4
// 374.172 us; speedup vs baseline: 1.8505x; 1.1826x over previous
//
#include <hip/hip_runtime.h>

#define NN 50000
#define NE 800000
#define ET 850000   // NE + NN self-loops
#define NG 64
#define D  128

typedef unsigned short u16;
typedef unsigned int   u32;

__device__ __forceinline__ float b2f(u16 u){
  union { u32 i; float f; } v; v.i = ((u32)u) << 16; return v.f;
}
__device__ __forceinline__ u16 f2b(float f){
  u32 u = __float_as_uint(f);
  u32 r = (u + 0x7fffu + ((u >> 16) & 1u)) >> 16;
  return (u16)r;
}
__device__ __forceinline__ u32 pack2(float a, float b){
  return (u32)f2b(a) | ((u32)f2b(b) << 16);
}

// ---------------- CSR build ----------------
__global__ void k_init(int* cnt, int* cur, float* bsum, float* bsq, float* pooled){
  int i = blockIdx.x*256 + threadIdx.x;
  if (i < NN){ cnt[i] = 1; cur[i] = 0; }   // 1 = self-loop
  if (i < 128){ bsum[i] = 0.f; bsq[i] = 0.f; }
  if (i < NG*D) pooled[i] = 0.f;
}

__global__ void k_hist(const int* __restrict__ dstE, int* __restrict__ cnt){
  int e = blockIdx.x*256 + threadIdx.x;
  if (e < NE) atomicAdd(&cnt[dstE[e]], 1);
}

__global__ void k_scan_a(const int* __restrict__ cnt, int* __restrict__ offs, int* __restrict__ bsums){
  __shared__ int s[256];
  int tid = threadIdx.x;
  int i = blockIdx.x*256 + tid;
  int v = (i < NN) ? cnt[i] : 0;
  s[tid] = v;
  __syncthreads();
  for (int off = 1; off < 256; off <<= 1){
    int t = (tid >= off) ? s[tid-off] : 0;
    __syncthreads();
    s[tid] += t;
    __syncthreads();
  }
  if (i < NN) offs[i] = s[tid] - v;          // exclusive within block
  if (tid == 255) bsums[blockIdx.x] = s[255];
}

__global__ void k_scan_b(const int* __restrict__ bsums, int* __restrict__ bbase){
  __shared__ int s[256];
  int tid = threadIdx.x;
  int v = (tid < 196) ? bsums[tid] : 0;
  s[tid] = v;
  __syncthreads();
  for (int off = 1; off < 256; off <<= 1){
    int t = (tid >= off) ? s[tid-off] : 0;
    __syncthreads();
    s[tid] += t;
    __syncthreads();
  }
  if (tid < 196) bbase[tid] = s[tid] - v;
}

__global__ void k_scan_c(int* __restrict__ offs, const int* __restrict__ bbase){
  int i = blockIdx.x*256 + threadIdx.x;
  if (i < NN) offs[i] += bbase[blockIdx.x];
  if (i == 0) offs[NN] = ET;
}

__global__ void k_scatter(const int* __restrict__ srcE, const int* __restrict__ dstE,
                          const int* __restrict__ offs, int* __restrict__ cur,
                          int* __restrict__ srcs){
  int i = blockIdx.x*256 + threadIdx.x;
  if (i >= ET) return;
  int s, d;
  if (i < NE){ s = srcE[i]; d = dstE[i]; } else { s = i - NE; d = s; }
  int pos = offs[d] + atomicAdd(&cur[d], 1);
  srcs[pos] = s;
}

// ---------------- GEMM: Ybf[n,128] = bf16( X[n,128] @ W[128,128] ), f32 accumulate ----
// BM=64, BK=32, 256 threads, thread = 4 rows x 8 cols (cols cg*4..+3 and 64+cg*4..+3)
__global__ __launch_bounds__(256) void k_gemm(const float* __restrict__ X, const float* __restrict__ W,
                                              u16* __restrict__ Ybf, int nrows){
  __shared__ float Xs[64*33];     // [row][k], stride 33 (2-way max on staging writes)
  __shared__ float Ws[32*128];    // [k][c]
  int tid = threadIdx.x;
  int cg = tid & 15, rg = tid >> 4;
  int row0 = blockIdx.x * 64;
  float acc[4][8];
  #pragma unroll
  for (int i = 0; i < 4; i++)
    #pragma unroll
    for (int j = 0; j < 8; j++) acc[i][j] = 0.f;

  for (int k0 = 0; k0 < 128; k0 += 32){
    float4 xr[2], wr[4];
    #pragma unroll
    for (int t = 0; t < 2; t++){
      int i = tid + t*256;          // 512 float4 = [64 rows][8 k4]
      int r = i >> 3, k4 = i & 7;
      int gr = row0 + r;
      xr[t] = (gr < nrows) ? ((const float4*)(X + (size_t)gr*D + k0))[k4]
                           : make_float4(0.f,0.f,0.f,0.f);
    }
    #pragma unroll
    for (int t = 0; t < 4; t++){
      int i = tid + t*256;          // 1024 float4 = [32 k][32 c4]
      int kk = i >> 5, c4 = i & 31;
      wr[t] = ((const float4*)(W + (size_t)(k0+kk)*D))[c4];
    }
    __syncthreads();                // protect previous chunk's reads
    #pragma unroll
    for (int t = 0; t < 2; t++){
      int i = tid + t*256;
      int r = i >> 3, k4 = i & 7;
      float* p = Xs + r*33 + k4*4;
      p[0] = xr[t].x; p[1] = xr[t].y; p[2] = xr[t].z; p[3] = xr[t].w;
    }
    #pragma unroll
    for (int t = 0; t < 4; t++){
      int i = tid + t*256;
      int kk = i >> 5, c4 = i & 31;
      ((float4*)Ws)[kk*32 + c4] = wr[t];
    }
    __syncthreads();
    #pragma unroll 4
    for (int k = 0; k < 32; k++){
      float x0 = Xs[(rg*4+0)*33 + k];
      float x1 = Xs[(rg*4+1)*33 + k];
      float x2 = Xs[(rg*4+2)*33 + k];
      float x3 = Xs[(rg*4+3)*33 + k];
      float4 wa = ((const float4*)Ws)[k*32 + cg];
      float4 wb = ((const float4*)Ws)[k*32 + 16 + cg];
      acc[0][0] = fmaf(x0, wa.x, acc[0][0]); acc[0][1] = fmaf(x0, wa.y, acc[0][1]);
      acc[0][2] = fmaf(x0, wa.z, acc[0][2]); acc[0][3] = fmaf(x0, wa.w, acc[0][3]);
      acc[0][4] = fmaf(x0, wb.x, acc[0][4]); acc[0][5] = fmaf(x0, wb.y, acc[0][5]);
      acc[0][6] = fmaf(x0, wb.z, acc[0][6]); acc[0][7] = fmaf(x0, wb.w, acc[0][7]);
      acc[1][0] = fmaf(x1, wa.x, acc[1][0]); acc[1][1] = fmaf(x1, wa.y, acc[1][1]);
      acc[1][2] = fmaf(x1, wa.z, acc[1][2]); acc[1][3] = fmaf(x1, wa.w, acc[1][3]);
      acc[1][4] = fmaf(x1, wb.x, acc[1][4]); acc[1][5] = fmaf(x1, wb.y, acc[1][5]);
      acc[1][6] = fmaf(x1, wb.z, acc[1][6]); acc[1][7] = fmaf(x1, wb.w, acc[1][7]);
      acc[2][0] = fmaf(x2, wa.x, acc[2][0]); acc[2][1] = fmaf(x2, wa.y, acc[2][1]);
      acc[2][2] = fmaf(x2, wa.z, acc[2][2]); acc[2][3] = fmaf(x2, wa.w, acc[2][3]);
      acc[2][4] = fmaf(x2, wb.x, acc[2][4]); acc[2][5] = fmaf(x2, wb.y, acc[2][5]);
      acc[2][6] = fmaf(x2, wb.z, acc[2][6]); acc[2][7] = fmaf(x2, wb.w, acc[2][7]);
      acc[3][0] = fmaf(x3, wa.x, acc[3][0]); acc[3][1] = fmaf(x3, wa.y, acc[3][1]);
      acc[3][2] = fmaf(x3, wa.z, acc[3][2]); acc[3][3] = fmaf(x3, wa.w, acc[3][3]);
      acc[3][4] = fmaf(x3, wb.x, acc[3][4]); acc[3][5] = fmaf(x3, wb.y, acc[3][5]);
      acc[3][6] = fmaf(x3, wb.z, acc[3][6]); acc[3][7] = fmaf(x3, wb.w, acc[3][7]);
    }
    __syncthreads();                // before next chunk's staging writes
  }
  #pragma unroll
  for (int i = 0; i < 4; i++){
    int gr = row0 + rg*4 + i;
    if (gr < nrows){
      uint2 lo, hi;
      lo.x = pack2(acc[i][0], acc[i][1]); lo.y = pack2(acc[i][2], acc[i][3]);
      hi.x = pack2(acc[i][4], acc[i][5]); hi.y = pack2(acc[i][6], acc[i][7]);
      *((uint2*)(Ybf + (size_t)gr*D + cg*4))      = lo;
      *((uint2*)(Ybf + (size_t)gr*D + 64 + cg*4)) = hi;
    }
  }
}

// ---------------- attention coefficients from bf16 h ----------------
__global__ void k_att(const u16* __restrict__ hb, const float* __restrict__ att_s,
                      const float* __restrict__ att_d, float* __restrict__ asrc,
                      float* __restrict__ adst){
  int tid = threadIdx.x;
  int c = tid & 127;
  int n = blockIdx.x*2 + (tid >> 7);
  float hv = b2f(hb[(size_t)n*D + c]);
  float ps = hv * att_s[c];
  float pd = hv * att_d[c];
  #pragma unroll
  for (int m = 1; m <= 16; m <<= 1){
    ps += __shfl_xor(ps, m);
    pd += __shfl_xor(pd, m);
  }
  if ((tid & 31) == 0){
    int head = c >> 5;
    asrc[n*4 + head] = ps;
    adst[n*4 + head] = pd;
  }
}

// ---------------- GAT edge softmax + aggregate (bf16 gather) ----------------
__global__ __launch_bounds__(256) void k_edge(
                       const u16* __restrict__ hb, const float* __restrict__ asrc,
                       const float* __restrict__ adst, const int* __restrict__ offs,
                       const int* __restrict__ srcs, const float* __restrict__ bias,
                       float* __restrict__ out){
  __shared__ int   sSrc[4][16];
  __shared__ float sAl[4][4][16];
  int w = threadIdx.x >> 6;
  int lane = threadIdx.x & 63;
  int n = blockIdx.x*4 + w;
  int off0 = offs[n];
  int deg  = offs[n+1] - off0;
  int hq = lane & 3;                       // head for phases 1-2
  float adn = adst[n*4 + hq];
  // phase 1: per-head max
  float m = -1e30f;
  for (int i = lane >> 2; i < deg; i += 16){
    int s = srcs[off0 + i];
    float e = asrc[s*4 + hq] + adn;
    e = e > 0.f ? e : 0.2f*e;
    m = fmaxf(m, e);
  }
  #pragma unroll
  for (int msk = 4; msk < 64; msk <<= 1) m = fmaxf(m, __shfl_xor(m, msk));
  // phase 2: per-head denom
  float sm = 0.f;
  for (int i = lane >> 2; i < deg; i += 16){
    int s = srcs[off0 + i];
    float e = asrc[s*4 + hq] + adn;
    e = e > 0.f ? e : 0.2f*e;
    sm += expf(e - m);
  }
  #pragma unroll
  for (int msk = 4; msk < 64; msk <<= 1) sm += __shfl_xor(sm, msk);
  // phase 3: cooperative alpha (1 exp/lane/chunk), unrolled bf16 gather
  int hd = lane >> 4, j16 = lane & 15;
  float mh  = __shfl(m, hd);
  float inv = 1.f / __shfl(sm, hd);
  float adh = __shfl(adn, hd);
  float2 acc = {0.f, 0.f};
  for (int base = 0; base < deg; base += 16){
    int lim = deg - base; if (lim > 16) lim = 16;
    int sj = 0; float al = 0.f;
    if (j16 < lim){
      sj = srcs[off0 + base + j16];
      float e = asrc[sj*4 + hd] + adh;
      e = e > 0.f ? e : 0.2f*e;
      al = expf(e - mh) * inv;
    }
    sSrc[w][j16] = sj;
    sAl[w][hd][j16] = al;
    int j = 0;
    for (; j + 4 <= lim; j += 4){
      int s0 = sSrc[w][j],   s1 = sSrc[w][j+1], s2 = sSrc[w][j+2], s3 = sSrc[w][j+3];
      float c0 = sAl[w][hd][j],   c1 = sAl[w][hd][j+1];
      float c2 = sAl[w][hd][j+2], c3 = sAl[w][hd][j+3];
      u32 u0 = ((const u32*)(hb + (size_t)s0*D))[lane];
      u32 u1 = ((const u32*)(hb + (size_t)s1*D))[lane];
      u32 u2 = ((const u32*)(hb + (size_t)s2*D))[lane];
      u32 u3 = ((const u32*)(hb + (size_t)s3*D))[lane];
      acc.x = fmaf(c0, __uint_as_float(u0 << 16), acc.x);
      acc.y = fmaf(c0, __uint_as_float(u0 & 0xffff0000u), acc.y);
      acc.x = fmaf(c1, __uint_as_float(u1 << 16), acc.x);
      acc.y = fmaf(c1, __uint_as_float(u1 & 0xffff0000u), acc.y);
      acc.x = fmaf(c2, __uint_as_float(u2 << 16), acc.x);
      acc.y = fmaf(c2, __uint_as_float(u2 & 0xffff0000u), acc.y);
      acc.x = fmaf(c3, __uint_as_float(u3 << 16), acc.x);
      acc.y = fmaf(c3, __uint_as_float(u3 & 0xffff0000u), acc.y);
    }
    for (; j < lim; j++){
      int s0 = sSrc[w][j];
      float c0 = sAl[w][hd][j];
      u32 u0 = ((const u32*)(hb + (size_t)s0*D))[lane];
      acc.x = fmaf(c0, __uint_as_float(u0 << 16), acc.x);
      acc.y = fmaf(c0, __uint_as_float(u0 & 0xffff0000u), acc.y);
    }
  }
  int c = lane*2;
  float2 o;
  o.x = acc.x + bias[c];
  o.y = acc.y + bias[c+1];
  ((float2*)(out + (size_t)n*D))[lane] = o;
}

// ---------------- BatchNorm ----------------
__global__ void k_bnstat(const float* __restrict__ B, float* __restrict__ bsum, float* __restrict__ bsq){
  int tid = threadIdx.x;
  int c = tid & 127;
  int r0 = blockIdx.x*2 + (tid >> 7);
  float s = 0.f, q = 0.f;
  for (int r = r0; r < NN; r += 512){
    float v = B[(size_t)r*D + c];
    s += v; q += v*v;
  }
  atomicAdd(&bsum[c], s);
  atomicAdd(&bsq[c], q);
}

__global__ void k_bnfin(const float* __restrict__ bsum, const float* __restrict__ bsq,
                        const float* __restrict__ gamma, const float* __restrict__ beta,
                        float* __restrict__ scale, float* __restrict__ shift){
  int c = threadIdx.x;  // 128
  float mu  = bsum[c] * (1.f/NN);
  float var = bsq[c] * (1.f/NN) - mu*mu;
  float sc  = gamma[c] * rsqrtf(var + 1e-5f);
  scale[c] = sc;
  shift[c] = beta[c] - mu*sc;
}

__global__ void k_bnapply(float* __restrict__ B, const float* __restrict__ scale,
                          const float* __restrict__ shift){
  int i = blockIdx.x*256 + threadIdx.x;     // over float4s
  if (i >= NN*D/4) return;
  float4 v = ((float4*)B)[i];
  int cb = i & 31;
  float4 sc = ((const float4*)scale)[cb];
  float4 sh = ((const float4*)shift)[cb];
  v.x = fmaf(v.x, sc.x, sh.x); v.y = fmaf(v.y, sc.y, sh.y);
  v.z = fmaf(v.z, sc.z, sh.z); v.w = fmaf(v.w, sc.w, sh.w);
  v.x = v.x > 0.f ? v.x : expm1f(v.x);
  v.y = v.y > 0.f ? v.y : expm1f(v.y);
  v.z = v.z > 0.f ? v.z : expm1f(v.z);
  v.w = v.w > 0.f ? v.w : expm1f(v.w);
  ((float4*)B)[i] = v;
}

// ---------------- global mean pool (batch sorted) ----------------
#define POOL_ROWS 50
__global__ void k_poolA(const float* __restrict__ h2, const int* __restrict__ batch,
                        float* __restrict__ pooled){
  int c = threadIdx.x & 127;
  int half = threadIdx.x >> 7;
  int r0 = blockIdx.x * POOL_ROWS;
  int r1 = r0 + POOL_ROWS; if (r1 > NN) r1 = NN;
  float s = 0.f; int g = -1;
  for (int r = r0 + half; r < r1; r += 2){
    int bg = batch[r];
    if (bg != g){
      if (g >= 0) atomicAdd(&pooled[g*D + c], s);
      g = bg; s = 0.f;
    }
    s += h2[(size_t)r*D + c];
  }
  if (g >= 0) atomicAdd(&pooled[g*D + c], s);
}

__global__ void k_poolB(const float* __restrict__ pooled, const int* __restrict__ batch,
                        float* __restrict__ out){
  int g = blockIdx.x;
  int c = threadIdx.x;   // 128
  int lo = 0, hi = NN;
  while (lo < hi){ int mid = (lo+hi) >> 1; if (batch[mid] < g) lo = mid+1; else hi = mid; }
  int a = lo, b = NN;
  while (a < b){ int mid = (a+b) >> 1; if (batch[mid] < g+1) a = mid+1; else b = mid; }
  int cntg = a - lo;
  out[g*D + c] = pooled[g*D + c] / (float)(cntg > 1 ? cntg : 1);
}

extern "C" void kernel_launch(void* const* d_in, const int* in_sizes, int n_in,
                              void* d_out, int out_size, void* d_ws, size_t ws_size,
                              hipStream_t stream){
  (void)in_sizes; (void)n_in; (void)out_size; (void)ws_size;
  const float* x   = (const float*)d_in[0];
  const int* ei    = (const int*)d_in[1];
  const int* batch = (const int*)d_in[2];
  const float* W1  = (const float*)d_in[3];
  const float* as1 = (const float*)d_in[4];
  const float* ad1 = (const float*)d_in[5];
  const float* b1  = (const float*)d_in[6];
  const float* g1  = (const float*)d_in[7];
  const float* be1 = (const float*)d_in[8];
  const float* W2  = (const float*)d_in[9];
  const float* as2 = (const float*)d_in[10];
  const float* ad2 = (const float*)d_in[11];
  const float* b2  = (const float*)d_in[12];
  float* outp = (float*)d_out;

  float* B    = (float*)d_ws;            // 6.4M f32
  float* asr  = B + 6400000;             // 200K
  float* ads  = asr + 200000;            // 200K
  float* bsum = ads + 200000;            // 128
  float* bsq  = bsum + 128;              // 128
  float* bsc  = bsq + 128;               // 128
  float* bsh  = bsc + 128;               // 128
  float* pooled = bsh + 128;             // 8192
  int* cnt    = (int*)(pooled + NG*D);   // 50000
  int* cur    = cnt + NN;                // 50000
  int* offs   = cur + NN;                // 50001
  int* srcs   = offs + (NN+1);           // 850000
  int* bsums  = srcs + ET;               // 256
  int* bbase  = bsums + 256;             // 256
  u16* hb     = (u16*)(bbase + 256);     // 6.4M bf16 (12.8 MB)

  const int* srcE = ei;
  const int* dstE = ei + NE;

  // CSR by destination (self-loops included)
  k_init<<<196, 256, 0, stream>>>(cnt, cur, bsum, bsq, pooled);
  k_hist<<<(NE+255)/256, 256, 0, stream>>>(dstE, cnt);
  k_scan_a<<<196, 256, 0, stream>>>(cnt, offs, bsums);
  k_scan_b<<<1, 256, 0, stream>>>(bsums, bbase);
  k_scan_c<<<196, 256, 0, stream>>>(offs, bbase);
  k_scatter<<<(ET+255)/256, 256, 0, stream>>>(srcE, dstE, offs, cur, srcs);

  // layer 1
  k_gemm<<<782, 256, 0, stream>>>(x, W1, hb, NN);
  k_att<<<NN/2, 256, 0, stream>>>(hb, as1, ad1, asr, ads);
  k_edge<<<NN/4, 256, 0, stream>>>(hb, asr, ads, offs, srcs, b1, B);
  // BN + ELU
  k_bnstat<<<256, 256, 0, stream>>>(B, bsum, bsq);
  k_bnfin<<<1, 128, 0, stream>>>(bsum, bsq, g1, be1, bsc, bsh);
  k_bnapply<<<(NN*D/4+255)/256, 256, 0, stream>>>(B, bsc, bsh);
  // layer 2
  k_gemm<<<782, 256, 0, stream>>>(B, W2, hb, NN);
  k_att<<<NN/2, 256, 0, stream>>>(hb, as2, ad2, asr, ads);
  k_edge<<<NN/4, 256, 0, stream>>>(hb, asr, ads, offs, srcs, b2, outp);
  // pool
  k_poolA<<<(NN + POOL_ROWS - 1)/POOL_ROWS, 256, 0, stream>>>(outp, batch, pooled);
  k_poolB<<<NG, 128, 0, stream>>>(pooled, batch, outp + 6400000);
}

// Round 5
// 318.998 us; speedup vs baseline: 2.1706x; 1.1730x over previous
//
#include <hip/hip_runtime.h>

#define NN 50000
#define NE 800000
#define ET 850000   // NE + NN self-loops
#define NG 64
#define D  128

typedef unsigned short u16;
typedef unsigned int   u32;

__device__ __forceinline__ u16 f2b(float f){
  u32 u = __float_as_uint(f);
  u32 r = (u + 0x7fffu + ((u >> 16) & 1u)) >> 16;
  return (u16)r;
}
__device__ __forceinline__ u32 pack2(float a, float b){
  return (u32)f2b(a) | ((u32)f2b(b) << 16);
}
__device__ __forceinline__ float lo16f(u32 u){ return __uint_as_float(u << 16); }
__device__ __forceinline__ float hi16f(u32 u){ return __uint_as_float(u & 0xffff0000u); }
__device__ __forceinline__ float b2f(u16 u){ return __uint_as_float(((u32)u) << 16); }

// ---------------- CSR build ----------------
__global__ void k_init(int* cnt, int* cur, float* bsum, float* bsq, float* pooled){
  int i = blockIdx.x*256 + threadIdx.x;
  if (i < NN){ cnt[i] = 1; cur[i] = 0; }   // 1 = self-loop
  if (i < 128){ bsum[i] = 0.f; bsq[i] = 0.f; }
  if (i < NG*D) pooled[i] = 0.f;
}

__global__ void k_hist(const int* __restrict__ dstE, int* __restrict__ cnt){
  int e = blockIdx.x*256 + threadIdx.x;
  if (e < NE) atomicAdd(&cnt[dstE[e]], 1);
}

__global__ void k_scan_a(const int* __restrict__ cnt, int* __restrict__ offs, int* __restrict__ bsums){
  __shared__ int s[256];
  int tid = threadIdx.x;
  int i = blockIdx.x*256 + tid;
  int v = (i < NN) ? cnt[i] : 0;
  s[tid] = v;
  __syncthreads();
  for (int off = 1; off < 256; off <<= 1){
    int t = (tid >= off) ? s[tid-off] : 0;
    __syncthreads();
    s[tid] += t;
    __syncthreads();
  }
  if (i < NN) offs[i] = s[tid] - v;          // exclusive within block
  if (tid == 255) bsums[blockIdx.x] = s[255];
}

__global__ void k_scan_b(const int* __restrict__ bsums, int* __restrict__ bbase){
  __shared__ int s[256];
  int tid = threadIdx.x;
  int v = (tid < 196) ? bsums[tid] : 0;
  s[tid] = v;
  __syncthreads();
  for (int off = 1; off < 256; off <<= 1){
    int t = (tid >= off) ? s[tid-off] : 0;
    __syncthreads();
    s[tid] += t;
    __syncthreads();
  }
  if (tid < 196) bbase[tid] = s[tid] - v;
}

__global__ void k_scan_c(int* __restrict__ offs, const int* __restrict__ bbase){
  int i = blockIdx.x*256 + threadIdx.x;
  if (i < NN) offs[i] += bbase[blockIdx.x];
  if (i == 0) offs[NN] = ET;
}

__global__ void k_scatter(const int* __restrict__ srcE, const int* __restrict__ dstE,
                          const int* __restrict__ offs, int* __restrict__ cur,
                          int* __restrict__ srcs){
  int i = blockIdx.x*256 + threadIdx.x;
  if (i >= ET) return;
  int s, d;
  if (i < NE){ s = srcE[i]; d = dstE[i]; } else { s = i - NE; d = s; }
  int pos = offs[d] + atomicAdd(&cur[d], 1);
  srcs[pos] = s;
}

// ---------------- GEMM + fused att dots (+ optional fused BN+ELU on input) ----------
// BM=64, BK=32, 256 threads, thread = 4 rows x 8 cols; emits bf16 h and per-node
// attention coefficients asrc/adst (computed from f32 accumulators).
template<int FUSE_BN>
__global__ __launch_bounds__(256) void k_gemm(const float* __restrict__ X, const float* __restrict__ W,
                                              u16* __restrict__ Ybf,
                                              const float* __restrict__ att_s, const float* __restrict__ att_d,
                                              float* __restrict__ asrc, float* __restrict__ adst,
                                              const float* __restrict__ bsc, const float* __restrict__ bsh,
                                              int nrows){
  __shared__ float Xs[64*33];     // [row][k], stride 33
  __shared__ float Ws[32*128];    // [k][c]
  int tid = threadIdx.x;
  int cg = tid & 15, rg = tid >> 4;
  int row0 = blockIdx.x * 64;
  float acc[4][8];
  #pragma unroll
  for (int i = 0; i < 4; i++)
    #pragma unroll
    for (int j = 0; j < 8; j++) acc[i][j] = 0.f;

  for (int k0 = 0; k0 < 128; k0 += 32){
    float4 xr[2], wr[4];
    #pragma unroll
    for (int t = 0; t < 2; t++){
      int i = tid + t*256;          // 512 float4 = [64 rows][8 k4]
      int r = i >> 3, k4 = i & 7;
      int gr = row0 + r;
      float4 v = (gr < nrows) ? ((const float4*)(X + (size_t)gr*D + k0))[k4]
                              : make_float4(0.f,0.f,0.f,0.f);
      if (FUSE_BN){
        float4 sc = ((const float4*)bsc)[(k0 >> 2) + k4];
        float4 sh = ((const float4*)bsh)[(k0 >> 2) + k4];
        v.x = fmaf(v.x, sc.x, sh.x); v.y = fmaf(v.y, sc.y, sh.y);
        v.z = fmaf(v.z, sc.z, sh.z); v.w = fmaf(v.w, sc.w, sh.w);
        v.x = v.x > 0.f ? v.x : expm1f(v.x);
        v.y = v.y > 0.f ? v.y : expm1f(v.y);
        v.z = v.z > 0.f ? v.z : expm1f(v.z);
        v.w = v.w > 0.f ? v.w : expm1f(v.w);
      }
      xr[t] = v;
    }
    #pragma unroll
    for (int t = 0; t < 4; t++){
      int i = tid + t*256;          // 1024 float4 = [32 k][32 c4]
      int kk = i >> 5, c4 = i & 31;
      wr[t] = ((const float4*)(W + (size_t)(k0+kk)*D))[c4];
    }
    __syncthreads();                // protect previous chunk's reads
    #pragma unroll
    for (int t = 0; t < 2; t++){
      int i = tid + t*256;
      int r = i >> 3, k4 = i & 7;
      float* p = Xs + r*33 + k4*4;
      p[0] = xr[t].x; p[1] = xr[t].y; p[2] = xr[t].z; p[3] = xr[t].w;
    }
    #pragma unroll
    for (int t = 0; t < 4; t++){
      int i = tid + t*256;
      int kk = i >> 5, c4 = i & 31;
      ((float4*)Ws)[kk*32 + c4] = wr[t];
    }
    __syncthreads();
    #pragma unroll 4
    for (int k = 0; k < 32; k++){
      float x0 = Xs[(rg*4+0)*33 + k];
      float x1 = Xs[(rg*4+1)*33 + k];
      float x2 = Xs[(rg*4+2)*33 + k];
      float x3 = Xs[(rg*4+3)*33 + k];
      float4 wa = ((const float4*)Ws)[k*32 + cg];
      float4 wb = ((const float4*)Ws)[k*32 + 16 + cg];
      acc[0][0] = fmaf(x0, wa.x, acc[0][0]); acc[0][1] = fmaf(x0, wa.y, acc[0][1]);
      acc[0][2] = fmaf(x0, wa.z, acc[0][2]); acc[0][3] = fmaf(x0, wa.w, acc[0][3]);
      acc[0][4] = fmaf(x0, wb.x, acc[0][4]); acc[0][5] = fmaf(x0, wb.y, acc[0][5]);
      acc[0][6] = fmaf(x0, wb.z, acc[0][6]); acc[0][7] = fmaf(x0, wb.w, acc[0][7]);
      acc[1][0] = fmaf(x1, wa.x, acc[1][0]); acc[1][1] = fmaf(x1, wa.y, acc[1][1]);
      acc[1][2] = fmaf(x1, wa.z, acc[1][2]); acc[1][3] = fmaf(x1, wa.w, acc[1][3]);
      acc[1][4] = fmaf(x1, wb.x, acc[1][4]); acc[1][5] = fmaf(x1, wb.y, acc[1][5]);
      acc[1][6] = fmaf(x1, wb.z, acc[1][6]); acc[1][7] = fmaf(x1, wb.w, acc[1][7]);
      acc[2][0] = fmaf(x2, wa.x, acc[2][0]); acc[2][1] = fmaf(x2, wa.y, acc[2][1]);
      acc[2][2] = fmaf(x2, wa.z, acc[2][2]); acc[2][3] = fmaf(x2, wa.w, acc[2][3]);
      acc[2][4] = fmaf(x2, wb.x, acc[2][4]); acc[2][5] = fmaf(x2, wb.y, acc[2][5]);
      acc[2][6] = fmaf(x2, wb.z, acc[2][6]); acc[2][7] = fmaf(x2, wb.w, acc[2][7]);
      acc[3][0] = fmaf(x3, wa.x, acc[3][0]); acc[3][1] = fmaf(x3, wa.y, acc[3][1]);
      acc[3][2] = fmaf(x3, wa.z, acc[3][2]); acc[3][3] = fmaf(x3, wa.w, acc[3][3]);
      acc[3][4] = fmaf(x3, wb.x, acc[3][4]); acc[3][5] = fmaf(x3, wb.y, acc[3][5]);
      acc[3][6] = fmaf(x3, wb.z, acc[3][6]); acc[3][7] = fmaf(x3, wb.w, acc[3][7]);
    }
    __syncthreads();                // before next chunk's staging writes
  }
  // fused attention dots: a[n,h] = sum_c h[n,h*32+c]*att[h,c]
  // lo quad: channels cg*4..+3 (head cg>>3); hi quad: channels 64+cg*4..+3 (head 2+(cg>>3))
  {
    float4 asl = ((const float4*)att_s)[cg];
    float4 ash = ((const float4*)att_s)[16 + cg];
    float4 adl = ((const float4*)att_d)[cg];
    float4 adh = ((const float4*)att_d)[16 + cg];
    #pragma unroll
    for (int i = 0; i < 4; i++){
      float psl = acc[i][0]*asl.x + acc[i][1]*asl.y + acc[i][2]*asl.z + acc[i][3]*asl.w;
      float psh = acc[i][4]*ash.x + acc[i][5]*ash.y + acc[i][6]*ash.z + acc[i][7]*ash.w;
      float pdl = acc[i][0]*adl.x + acc[i][1]*adl.y + acc[i][2]*adl.z + acc[i][3]*adl.w;
      float pdh = acc[i][4]*adh.x + acc[i][5]*adh.y + acc[i][6]*adh.z + acc[i][7]*adh.w;
      #pragma unroll
      for (int msk = 1; msk <= 4; msk <<= 1){
        psl += __shfl_xor(psl, msk);
        psh += __shfl_xor(psh, msk);
        pdl += __shfl_xor(pdl, msk);
        pdh += __shfl_xor(pdh, msk);
      }
      int gr = row0 + rg*4 + i;
      if ((cg & 7) == 0 && gr < nrows){
        int hl = cg >> 3;
        asrc[gr*4 + hl]   = psl;
        asrc[gr*4 + 2+hl] = psh;
        adst[gr*4 + hl]   = pdl;
        adst[gr*4 + 2+hl] = pdh;
      }
    }
  }
  #pragma unroll
  for (int i = 0; i < 4; i++){
    int gr = row0 + rg*4 + i;
    if (gr < nrows){
      uint2 lo, hi;
      lo.x = pack2(acc[i][0], acc[i][1]); lo.y = pack2(acc[i][2], acc[i][3]);
      hi.x = pack2(acc[i][4], acc[i][5]); hi.y = pack2(acc[i][6], acc[i][7]);
      *((uint2*)(Ybf + (size_t)gr*D + cg*4))      = lo;
      *((uint2*)(Ybf + (size_t)gr*D + 64 + cg*4)) = hi;
    }
  }
}

// ---------------- GAT edge softmax + aggregate: flash-style single pass ----------------
// wave per dst node. alpha-lanes: (hd = lane>>4, j16 = lane&15). gather-lanes:
// half = lane>>5 takes edges of that parity, q = lane&31 owns channels q*4..+3.
__global__ __launch_bounds__(256) void k_edge(
                       const u16* __restrict__ hb, const float* __restrict__ asrc,
                       const float* __restrict__ adst, const int* __restrict__ offs,
                       const int* __restrict__ srcs, const float* __restrict__ bias,
                       float* __restrict__ out){
  __shared__ int   sSrc[4][16];
  __shared__ float sAl[4][4][16];
  __shared__ float sScale[4][4];
  int w = threadIdx.x >> 6;
  int lane = threadIdx.x & 63;
  int n = blockIdx.x*4 + w;
  int off0 = offs[n];
  int deg  = offs[n+1] - off0;
  int hd = lane >> 4, j16 = lane & 15;
  float adh = adst[n*4 + hd];
  int half = lane >> 5, q = lane & 31;
  int hg = q >> 3;
  float m = -1e30f, den = 0.f;
  float acc0 = 0.f, acc1 = 0.f, acc2 = 0.f, acc3 = 0.f;

  for (int base = 0; base < deg; base += 16){
    int lim = deg - base; if (lim > 16) lim = 16;
    // ---- alpha compute (online softmax) ----
    int sj; float e;
    if (j16 < lim){
      sj = srcs[off0 + base + j16];
      e = asrc[sj*4 + hd] + adh;
      e = e > 0.f ? e : 0.2f*e;
    } else { sj = srcs[off0]; e = -1e30f; }
    float cm = e;
    cm = fmaxf(cm, __shfl_xor(cm, 1));
    cm = fmaxf(cm, __shfl_xor(cm, 2));
    cm = fmaxf(cm, __shfl_xor(cm, 4));
    cm = fmaxf(cm, __shfl_xor(cm, 8));
    float mn = fmaxf(m, cm);
    float sc = expf(m - mn);
    float al = (j16 < lim) ? expf(e - mn) : 0.f;
    float ss = al;
    ss += __shfl_xor(ss, 1);
    ss += __shfl_xor(ss, 2);
    ss += __shfl_xor(ss, 4);
    ss += __shfl_xor(ss, 8);
    den = den*sc + ss;
    m = mn;
    sSrc[w][j16] = sj;                 // 4 head groups write identical values
    sAl[w][hd][j16] = al;
    if (j16 == 0) sScale[w][hd] = sc;
    // ---- gather + accumulate (paired: half-wave per edge parity) ----
    float gsc = sScale[w][hg];
    acc0 *= gsc; acc1 *= gsc; acc2 *= gsc; acc3 *= gsc;
    for (int j = 0; j < lim; j += 8){
      int sA = sSrc[w][j + half];
      int sB = sSrc[w][j + 2 + half];
      int sC = sSrc[w][j + 4 + half];
      int sD = sSrc[w][j + 6 + half];
      float aA = sAl[w][hg][j + half];
      float aB = sAl[w][hg][j + 2 + half];
      float aC = sAl[w][hg][j + 4 + half];
      float aD = sAl[w][hg][j + 6 + half];
      uint2 vA = ((const uint2*)(hb + (size_t)sA*D))[q];
      uint2 vB = ((const uint2*)(hb + (size_t)sB*D))[q];
      uint2 vC = ((const uint2*)(hb + (size_t)sC*D))[q];
      uint2 vD = ((const uint2*)(hb + (size_t)sD*D))[q];
      acc0 = fmaf(aA, lo16f(vA.x), acc0); acc1 = fmaf(aA, hi16f(vA.x), acc1);
      acc2 = fmaf(aA, lo16f(vA.y), acc2); acc3 = fmaf(aA, hi16f(vA.y), acc3);
      acc0 = fmaf(aB, lo16f(vB.x), acc0); acc1 = fmaf(aB, hi16f(vB.x), acc1);
      acc2 = fmaf(aB, lo16f(vB.y), acc2); acc3 = fmaf(aB, hi16f(vB.y), acc3);
      acc0 = fmaf(aC, lo16f(vC.x), acc0); acc1 = fmaf(aC, hi16f(vC.x), acc1);
      acc2 = fmaf(aC, lo16f(vC.y), acc2); acc3 = fmaf(aC, hi16f(vC.y), acc3);
      acc0 = fmaf(aD, lo16f(vD.x), acc0); acc1 = fmaf(aD, hi16f(vD.x), acc1);
      acc2 = fmaf(aD, lo16f(vD.y), acc2); acc3 = fmaf(aD, hi16f(vD.y), acc3);
    }
  }
  // combine the two half-wave partial sums (each holds other parity's edges)
  acc0 += __shfl_xor(acc0, 32);
  acc1 += __shfl_xor(acc1, 32);
  acc2 += __shfl_xor(acc2, 32);
  acc3 += __shfl_xor(acc3, 32);
  float dh = __shfl(den, hg*16);
  float inv = 1.f / dh;
  if (half == 0){
    int cb = q*4;
    float4 o;
    o.x = fmaf(acc0, inv, 0.f) + bias[cb];
    o.y = fmaf(acc1, inv, 0.f) + bias[cb+1];
    o.z = fmaf(acc2, inv, 0.f) + bias[cb+2];
    o.w = fmaf(acc3, inv, 0.f) + bias[cb+3];
    ((float4*)(out + (size_t)n*D))[q] = o;
  }
}

// ---------------- BatchNorm stats ----------------
__global__ void k_bnstat(const float* __restrict__ B, float* __restrict__ bsum, float* __restrict__ bsq){
  int tid = threadIdx.x;
  int c = tid & 127;
  int r0 = blockIdx.x*2 + (tid >> 7);
  float s = 0.f, q = 0.f;
  for (int r = r0; r < NN; r += 512){
    float v = B[(size_t)r*D + c];
    s += v; q += v*v;
  }
  atomicAdd(&bsum[c], s);
  atomicAdd(&bsq[c], q);
}

__global__ void k_bnfin(const float* __restrict__ bsum, const float* __restrict__ bsq,
                        const float* __restrict__ gamma, const float* __restrict__ beta,
                        float* __restrict__ scale, float* __restrict__ shift){
  int c = threadIdx.x;  // 128
  float mu  = bsum[c] * (1.f/NN);
  float var = bsq[c] * (1.f/NN) - mu*mu;
  float sc  = gamma[c] * rsqrtf(var + 1e-5f);
  scale[c] = sc;
  shift[c] = beta[c] - mu*sc;
}

// ---------------- global mean pool (batch sorted) ----------------
#define POOL_ROWS 50
__global__ void k_poolA(const float* __restrict__ h2, const int* __restrict__ batch,
                        float* __restrict__ pooled){
  int c = threadIdx.x & 127;
  int half = threadIdx.x >> 7;
  int r0 = blockIdx.x * POOL_ROWS;
  int r1 = r0 + POOL_ROWS; if (r1 > NN) r1 = NN;
  float s = 0.f; int g = -1;
  for (int r = r0 + half; r < r1; r += 2){
    int bg = batch[r];
    if (bg != g){
      if (g >= 0) atomicAdd(&pooled[g*D + c], s);
      g = bg; s = 0.f;
    }
    s += h2[(size_t)r*D + c];
  }
  if (g >= 0) atomicAdd(&pooled[g*D + c], s);
}

__global__ void k_poolB(const float* __restrict__ pooled, const int* __restrict__ batch,
                        float* __restrict__ out){
  int g = blockIdx.x;
  int c = threadIdx.x;   // 128
  int lo = 0, hi = NN;
  while (lo < hi){ int mid = (lo+hi) >> 1; if (batch[mid] < g) lo = mid+1; else hi = mid; }
  int a = lo, b = NN;
  while (a < b){ int mid = (a+b) >> 1; if (batch[mid] < g+1) a = mid+1; else b = mid; }
  int cntg = a - lo;
  out[g*D + c] = pooled[g*D + c] / (float)(cntg > 1 ? cntg : 1);
}

extern "C" void kernel_launch(void* const* d_in, const int* in_sizes, int n_in,
                              void* d_out, int out_size, void* d_ws, size_t ws_size,
                              hipStream_t stream){
  (void)in_sizes; (void)n_in; (void)out_size; (void)ws_size;
  const float* x   = (const float*)d_in[0];
  const int* ei    = (const int*)d_in[1];
  const int* batch = (const int*)d_in[2];
  const float* W1  = (const float*)d_in[3];
  const float* as1 = (const float*)d_in[4];
  const float* ad1 = (const float*)d_in[5];
  const float* b1  = (const float*)d_in[6];
  const float* g1  = (const float*)d_in[7];
  const float* be1 = (const float*)d_in[8];
  const float* W2  = (const float*)d_in[9];
  const float* as2 = (const float*)d_in[10];
  const float* ad2 = (const float*)d_in[11];
  const float* b2  = (const float*)d_in[12];
  float* outp = (float*)d_out;

  float* B    = (float*)d_ws;            // 6.4M f32
  float* asr  = B + 6400000;             // 200K
  float* ads  = asr + 200000;            // 200K
  float* bsum = ads + 200000;            // 128
  float* bsq  = bsum + 128;              // 128
  float* bsc  = bsq + 128;               // 128
  float* bsh  = bsc + 128;               // 128
  float* pooled = bsh + 128;             // 8192
  int* cnt    = (int*)(pooled + NG*D);   // 50000
  int* cur    = cnt + NN;                // 50000
  int* offs   = cur + NN;                // 50001
  int* srcs   = offs + (NN+1);           // 850000
  int* bsums  = srcs + ET;               // 256
  int* bbase  = bsums + 256;             // 256
  u16* hb     = (u16*)(bbase + 256);     // 6.4M bf16 (12.8 MB)

  const int* srcE = ei;
  const int* dstE = ei + NE;

  // CSR by destination (self-loops included)
  k_init<<<196, 256, 0, stream>>>(cnt, cur, bsum, bsq, pooled);
  k_hist<<<(NE+255)/256, 256, 0, stream>>>(dstE, cnt);
  k_scan_a<<<196, 256, 0, stream>>>(cnt, offs, bsums);
  k_scan_b<<<1, 256, 0, stream>>>(bsums, bbase);
  k_scan_c<<<196, 256, 0, stream>>>(offs, bbase);
  k_scatter<<<(ET+255)/256, 256, 0, stream>>>(srcE, dstE, offs, cur, srcs);

  // layer 1: GEMM (+att dots) -> edge softmax/aggregate -> BN stats
  k_gemm<0><<<782, 256, 0, stream>>>(x, W1, hb, as1, ad1, asr, ads, nullptr, nullptr, NN);
  k_edge<<<NN/4, 256, 0, stream>>>(hb, asr, ads, offs, srcs, b1, B);
  k_bnstat<<<256, 256, 0, stream>>>(B, bsum, bsq);
  k_bnfin<<<1, 128, 0, stream>>>(bsum, bsq, g1, be1, bsc, bsh);
  // layer 2: GEMM with fused BN+ELU on input (+att dots) -> edge -> pool
  k_gemm<1><<<782, 256, 0, stream>>>(B, W2, hb, as2, ad2, asr, ads, bsc, bsh, NN);
  k_edge<<<NN/4, 256, 0, stream>>>(hb, asr, ads, offs, srcs, b2, outp);
  k_poolA<<<(NN + POOL_ROWS - 1)/POOL_ROWS, 256, 0, stream>>>(outp, batch, pooled);
  k_poolB<<<NG, 128, 0, stream>>>(pooled, batch, outp + 6400000);
}

// Round 6
// 309.086 us; speedup vs baseline: 2.2402x; 1.0321x over previous
//
#include <hip/hip_runtime.h>

#define NN 50000
#define NE 800000
#define ET 850000   // NE + NN self-loops
#define NG 64
#define D  128

typedef unsigned short u16;
typedef unsigned int   u32;

__device__ __forceinline__ u16 f2b(float f){
  u32 u = __float_as_uint(f);
  u32 r = (u + 0x7fffu + ((u >> 16) & 1u)) >> 16;
  return (u16)r;
}
__device__ __forceinline__ u32 pack2(float a, float b){
  return (u32)f2b(a) | ((u32)f2b(b) << 16);
}
__device__ __forceinline__ float lo16f(u32 u){ return __uint_as_float(u << 16); }
__device__ __forceinline__ float hi16f(u32 u){ return __uint_as_float(u & 0xffff0000u); }

// ---------------- init ----------------
__global__ void k_init(int* cnt, int* cur, float* bsum, float* bsq, float* pooled){
  int i = blockIdx.x*256 + threadIdx.x;
  if (i < NN){ cnt[i] = 1; cur[i] = 0; }   // 1 = self-loop
  if (i < 128){ bsum[i] = 0.f; bsq[i] = 0.f; }
  if (i < NG*D) pooled[i] = 0.f;
}

// ---------------- scans ----------------
__global__ void k_scan_a(const int* __restrict__ cnt, int* __restrict__ offs, int* __restrict__ bsums){
  __shared__ int s[256];
  int tid = threadIdx.x;
  int i = blockIdx.x*256 + tid;
  int v = (i < NN) ? cnt[i] : 0;
  s[tid] = v;
  __syncthreads();
  for (int off = 1; off < 256; off <<= 1){
    int t = (tid >= off) ? s[tid-off] : 0;
    __syncthreads();
    s[tid] += t;
    __syncthreads();
  }
  if (i < NN) offs[i] = s[tid] - v;          // exclusive within block
  if (tid == 255) bsums[blockIdx.x] = s[255];
}

// merged scan_b + scan_c: every block recomputes the block-sum prefix
__global__ void k_scan_c2(int* __restrict__ offs, const int* __restrict__ bsums){
  __shared__ int s[256];
  int tid = threadIdx.x;
  s[tid] = (tid < 196) ? bsums[tid] : 0;
  __syncthreads();
  for (int off = 1; off < 256; off <<= 1){
    int t = (tid >= off) ? s[tid-off] : 0;
    __syncthreads();
    s[tid] += t;
    __syncthreads();
  }
  int base = (blockIdx.x == 0) ? 0 : s[blockIdx.x - 1];
  int i = blockIdx.x*256 + tid;
  if (i < NN) offs[i] += base;
  if (i == 0) offs[NN] = ET;
}

__global__ void k_scatter(const int* __restrict__ srcE, const int* __restrict__ dstE,
                          const int* __restrict__ offs, int* __restrict__ cur,
                          int* __restrict__ srcs){
  int i = blockIdx.x*256 + threadIdx.x;
  if (i >= ET) return;
  int s, d;
  if (i < NE){ s = srcE[i]; d = dstE[i]; } else { s = i - NE; d = s; }
  int pos = offs[d] + atomicAdd(&cur[d], 1);
  srcs[pos] = s;
}

// ---------------- GEMM + fused att dots; FUSE=0 also does edge histogram,
// FUSE=1 also computes BN scale/shift in LDS and applies BN+ELU to X --------
template<int FUSE>
__global__ __launch_bounds__(256) void k_gemm(const float* __restrict__ X, const float* __restrict__ W,
                                              u16* __restrict__ Ybf,
                                              const float* __restrict__ att_s, const float* __restrict__ att_d,
                                              float* __restrict__ asrc, float* __restrict__ adst,
                                              const int* __restrict__ dstE, int* __restrict__ cnt,
                                              const float* __restrict__ bsum, const float* __restrict__ bsq,
                                              const float* __restrict__ gamma, const float* __restrict__ beta,
                                              int nrows){
  __shared__ float Xs[64*33];     // [row][k], stride 33
  __shared__ float Ws[32*128];    // [k][c]
  __shared__ float sBsc[128], sBsh[128];
  int tid = threadIdx.x;
  if (FUSE == 0){
    // fused destination histogram (atomics overlap the GEMM)
    for (int e = blockIdx.x*256 + tid; e < NE; e += gridDim.x*256)
      atomicAdd(&cnt[dstE[e]], 1);
  }
  if (FUSE == 1){
    if (tid < 128){
      float mu  = bsum[tid] * (1.f/NN);
      float var = bsq[tid] * (1.f/NN) - mu*mu;
      float sc  = gamma[tid] * rsqrtf(var + 1e-5f);
      sBsc[tid] = sc;
      sBsh[tid] = beta[tid] - mu*sc;
    }
    __syncthreads();
  }
  int cg = tid & 15, rg = tid >> 4;
  int row0 = blockIdx.x * 64;
  float acc[4][8];
  #pragma unroll
  for (int i = 0; i < 4; i++)
    #pragma unroll
    for (int j = 0; j < 8; j++) acc[i][j] = 0.f;

  for (int k0 = 0; k0 < 128; k0 += 32){
    float4 xr[2], wr[4];
    #pragma unroll
    for (int t = 0; t < 2; t++){
      int i = tid + t*256;          // 512 float4 = [64 rows][8 k4]
      int r = i >> 3, k4 = i & 7;
      int gr = row0 + r;
      float4 v = (gr < nrows) ? ((const float4*)(X + (size_t)gr*D + k0))[k4]
                              : make_float4(0.f,0.f,0.f,0.f);
      if (FUSE == 1){
        float4 sc = ((const float4*)sBsc)[(k0 >> 2) + k4];
        float4 sh = ((const float4*)sBsh)[(k0 >> 2) + k4];
        v.x = fmaf(v.x, sc.x, sh.x); v.y = fmaf(v.y, sc.y, sh.y);
        v.z = fmaf(v.z, sc.z, sh.z); v.w = fmaf(v.w, sc.w, sh.w);
        v.x = v.x > 0.f ? v.x : expm1f(v.x);
        v.y = v.y > 0.f ? v.y : expm1f(v.y);
        v.z = v.z > 0.f ? v.z : expm1f(v.z);
        v.w = v.w > 0.f ? v.w : expm1f(v.w);
      }
      xr[t] = v;
    }
    #pragma unroll
    for (int t = 0; t < 4; t++){
      int i = tid + t*256;          // 1024 float4 = [32 k][32 c4]
      int kk = i >> 5, c4 = i & 31;
      wr[t] = ((const float4*)(W + (size_t)(k0+kk)*D))[c4];
    }
    __syncthreads();                // protect previous chunk's reads
    #pragma unroll
    for (int t = 0; t < 2; t++){
      int i = tid + t*256;
      int r = i >> 3, k4 = i & 7;
      float* p = Xs + r*33 + k4*4;
      p[0] = xr[t].x; p[1] = xr[t].y; p[2] = xr[t].z; p[3] = xr[t].w;
    }
    #pragma unroll
    for (int t = 0; t < 4; t++){
      int i = tid + t*256;
      int kk = i >> 5, c4 = i & 31;
      ((float4*)Ws)[kk*32 + c4] = wr[t];
    }
    __syncthreads();
    #pragma unroll 4
    for (int k = 0; k < 32; k++){
      float x0 = Xs[(rg*4+0)*33 + k];
      float x1 = Xs[(rg*4+1)*33 + k];
      float x2 = Xs[(rg*4+2)*33 + k];
      float x3 = Xs[(rg*4+3)*33 + k];
      float4 wa = ((const float4*)Ws)[k*32 + cg];
      float4 wb = ((const float4*)Ws)[k*32 + 16 + cg];
      acc[0][0] = fmaf(x0, wa.x, acc[0][0]); acc[0][1] = fmaf(x0, wa.y, acc[0][1]);
      acc[0][2] = fmaf(x0, wa.z, acc[0][2]); acc[0][3] = fmaf(x0, wa.w, acc[0][3]);
      acc[0][4] = fmaf(x0, wb.x, acc[0][4]); acc[0][5] = fmaf(x0, wb.y, acc[0][5]);
      acc[0][6] = fmaf(x0, wb.z, acc[0][6]); acc[0][7] = fmaf(x0, wb.w, acc[0][7]);
      acc[1][0] = fmaf(x1, wa.x, acc[1][0]); acc[1][1] = fmaf(x1, wa.y, acc[1][1]);
      acc[1][2] = fmaf(x1, wa.z, acc[1][2]); acc[1][3] = fmaf(x1, wa.w, acc[1][3]);
      acc[1][4] = fmaf(x1, wb.x, acc[1][4]); acc[1][5] = fmaf(x1, wb.y, acc[1][5]);
      acc[1][6] = fmaf(x1, wb.z, acc[1][6]); acc[1][7] = fmaf(x1, wb.w, acc[1][7]);
      acc[2][0] = fmaf(x2, wa.x, acc[2][0]); acc[2][1] = fmaf(x2, wa.y, acc[2][1]);
      acc[2][2] = fmaf(x2, wa.z, acc[2][2]); acc[2][3] = fmaf(x2, wa.w, acc[2][3]);
      acc[2][4] = fmaf(x2, wb.x, acc[2][4]); acc[2][5] = fmaf(x2, wb.y, acc[2][5]);
      acc[2][6] = fmaf(x2, wb.z, acc[2][6]); acc[2][7] = fmaf(x2, wb.w, acc[2][7]);
      acc[3][0] = fmaf(x3, wa.x, acc[3][0]); acc[3][1] = fmaf(x3, wa.y, acc[3][1]);
      acc[3][2] = fmaf(x3, wa.z, acc[3][2]); acc[3][3] = fmaf(x3, wa.w, acc[3][3]);
      acc[3][4] = fmaf(x3, wb.x, acc[3][4]); acc[3][5] = fmaf(x3, wb.y, acc[3][5]);
      acc[3][6] = fmaf(x3, wb.z, acc[3][6]); acc[3][7] = fmaf(x3, wb.w, acc[3][7]);
    }
    __syncthreads();                // before next chunk's staging writes
  }
  // fused attention dots: a[n,h] = sum_c h[n,h*32+c]*att[h,c]
  {
    float4 asl = ((const float4*)att_s)[cg];
    float4 ash = ((const float4*)att_s)[16 + cg];
    float4 adl = ((const float4*)att_d)[cg];
    float4 adh = ((const float4*)att_d)[16 + cg];
    #pragma unroll
    for (int i = 0; i < 4; i++){
      float psl = acc[i][0]*asl.x + acc[i][1]*asl.y + acc[i][2]*asl.z + acc[i][3]*asl.w;
      float psh = acc[i][4]*ash.x + acc[i][5]*ash.y + acc[i][6]*ash.z + acc[i][7]*ash.w;
      float pdl = acc[i][0]*adl.x + acc[i][1]*adl.y + acc[i][2]*adl.z + acc[i][3]*adl.w;
      float pdh = acc[i][4]*adh.x + acc[i][5]*adh.y + acc[i][6]*adh.z + acc[i][7]*adh.w;
      #pragma unroll
      for (int msk = 1; msk <= 4; msk <<= 1){
        psl += __shfl_xor(psl, msk);
        psh += __shfl_xor(psh, msk);
        pdl += __shfl_xor(pdl, msk);
        pdh += __shfl_xor(pdh, msk);
      }
      int gr = row0 + rg*4 + i;
      if ((cg & 7) == 0 && gr < nrows){
        int hl = cg >> 3;
        asrc[gr*4 + hl]   = psl;
        asrc[gr*4 + 2+hl] = psh;
        adst[gr*4 + hl]   = pdl;
        adst[gr*4 + 2+hl] = pdh;
      }
    }
  }
  #pragma unroll
  for (int i = 0; i < 4; i++){
    int gr = row0 + rg*4 + i;
    if (gr < nrows){
      uint2 lo, hi;
      lo.x = pack2(acc[i][0], acc[i][1]); lo.y = pack2(acc[i][2], acc[i][3]);
      hi.x = pack2(acc[i][4], acc[i][5]); hi.y = pack2(acc[i][6], acc[i][7]);
      *((uint2*)(Ybf + (size_t)gr*D + cg*4))      = lo;
      *((uint2*)(Ybf + (size_t)gr*D + 64 + cg*4)) = hi;
    }
  }
}

// ---------------- GAT edge softmax + aggregate: single pass, no max shift ------
// e is bounded (|e| < ~10) so exp(e) is safe in f32; softmax is shift-invariant.
// alpha lanes: (hd = lane>>4, j16 = lane&15). gather lanes: half = lane>>5 takes
// edges of that parity, q = lane&31 owns channels q*4..+3 (head hg = q>>3).
__global__ __launch_bounds__(256) void k_edge(
                       const u16* __restrict__ hb, const float* __restrict__ asrc,
                       const float* __restrict__ adst, const int* __restrict__ offs,
                       const int* __restrict__ srcs, const float* __restrict__ bias,
                       float* __restrict__ out){
  __shared__ uint2 sPk[4][4][16];   // {byte offset src*256, alpha bits}
  int w = threadIdx.x >> 6;
  int lane = threadIdx.x & 63;
  int n = blockIdx.x*4 + w;
  int off0 = offs[n];
  int deg  = offs[n+1] - off0;
  int hd = lane >> 4, j16 = lane & 15;
  float adh = adst[n*4 + hd];
  int half = lane >> 5, q = lane & 31;
  int hg = q >> 3;
  int qb = q*8;
  float denp = 0.f;
  float acc0=0.f, acc1=0.f, acc2=0.f, acc3=0.f;
  const char* hbase = (const char*)hb;
  const int* sp = srcs + off0;
  for (int base = 0; base < deg; base += 16){
    int lim = deg - base; if (lim > 16) lim = 16;
    int sj; float al;
    if (j16 < lim){
      sj = sp[base + j16];
      float e = asrc[sj*4 + hd] + adh;
      e = e > 0.f ? e : 0.2f*e;
      al = __expf(e);
    } else { sj = 0; al = 0.f; }
    denp += al;
    sPk[w][hd][j16] = make_uint2((u32)sj << 8, __float_as_uint(al));
    if (lim == 16){
      uint2 p0 = sPk[w][hg][half],      p1 = sPk[w][hg][2+half];
      uint2 p2 = sPk[w][hg][4+half],    p3 = sPk[w][hg][6+half];
      uint2 p4 = sPk[w][hg][8+half],    p5 = sPk[w][hg][10+half];
      uint2 p6 = sPk[w][hg][12+half],   p7 = sPk[w][hg][14+half];
      uint2 v0 = *(const uint2*)(hbase + p0.x + qb);
      uint2 v1 = *(const uint2*)(hbase + p1.x + qb);
      uint2 v2 = *(const uint2*)(hbase + p2.x + qb);
      uint2 v3 = *(const uint2*)(hbase + p3.x + qb);
      uint2 v4 = *(const uint2*)(hbase + p4.x + qb);
      uint2 v5 = *(const uint2*)(hbase + p5.x + qb);
      uint2 v6 = *(const uint2*)(hbase + p6.x + qb);
      uint2 v7 = *(const uint2*)(hbase + p7.x + qb);
      float a0 = __uint_as_float(p0.y), a1 = __uint_as_float(p1.y);
      float a2 = __uint_as_float(p2.y), a3 = __uint_as_float(p3.y);
      float a4 = __uint_as_float(p4.y), a5 = __uint_as_float(p5.y);
      float a6 = __uint_as_float(p6.y), a7 = __uint_as_float(p7.y);
      acc0 = fmaf(a0, lo16f(v0.x), acc0); acc1 = fmaf(a0, hi16f(v0.x), acc1);
      acc2 = fmaf(a0, lo16f(v0.y), acc2); acc3 = fmaf(a0, hi16f(v0.y), acc3);
      acc0 = fmaf(a1, lo16f(v1.x), acc0); acc1 = fmaf(a1, hi16f(v1.x), acc1);
      acc2 = fmaf(a1, lo16f(v1.y), acc2); acc3 = fmaf(a1, hi16f(v1.y), acc3);
      acc0 = fmaf(a2, lo16f(v2.x), acc0); acc1 = fmaf(a2, hi16f(v2.x), acc1);
      acc2 = fmaf(a2, lo16f(v2.y), acc2); acc3 = fmaf(a2, hi16f(v2.y), acc3);
      acc0 = fmaf(a3, lo16f(v3.x), acc0); acc1 = fmaf(a3, hi16f(v3.x), acc1);
      acc2 = fmaf(a3, lo16f(v3.y), acc2); acc3 = fmaf(a3, hi16f(v3.y), acc3);
      acc0 = fmaf(a4, lo16f(v4.x), acc0); acc1 = fmaf(a4, hi16f(v4.x), acc1);
      acc2 = fmaf(a4, lo16f(v4.y), acc2); acc3 = fmaf(a4, hi16f(v4.y), acc3);
      acc0 = fmaf(a5, lo16f(v5.x), acc0); acc1 = fmaf(a5, hi16f(v5.x), acc1);
      acc2 = fmaf(a5, lo16f(v5.y), acc2); acc3 = fmaf(a5, hi16f(v5.y), acc3);
      acc0 = fmaf(a6, lo16f(v6.x), acc0); acc1 = fmaf(a6, hi16f(v6.x), acc1);
      acc2 = fmaf(a6, lo16f(v6.y), acc2); acc3 = fmaf(a6, hi16f(v6.y), acc3);
      acc0 = fmaf(a7, lo16f(v7.x), acc0); acc1 = fmaf(a7, hi16f(v7.x), acc1);
      acc2 = fmaf(a7, lo16f(v7.y), acc2); acc3 = fmaf(a7, hi16f(v7.y), acc3);
    } else {
      for (int j = 0; j < lim; j += 8){
        uint2 pA = sPk[w][hg][j+half],   pB = sPk[w][hg][j+2+half];
        uint2 pC = sPk[w][hg][j+4+half], pD = sPk[w][hg][j+6+half];
        uint2 vA = *(const uint2*)(hbase + pA.x + qb);
        uint2 vB = *(const uint2*)(hbase + pB.x + qb);
        uint2 vC = *(const uint2*)(hbase + pC.x + qb);
        uint2 vD = *(const uint2*)(hbase + pD.x + qb);
        float aA = __uint_as_float(pA.y), aB = __uint_as_float(pB.y);
        float aC = __uint_as_float(pC.y), aD = __uint_as_float(pD.y);
        acc0 = fmaf(aA, lo16f(vA.x), acc0); acc1 = fmaf(aA, hi16f(vA.x), acc1);
        acc2 = fmaf(aA, lo16f(vA.y), acc2); acc3 = fmaf(aA, hi16f(vA.y), acc3);
        acc0 = fmaf(aB, lo16f(vB.x), acc0); acc1 = fmaf(aB, hi16f(vB.x), acc1);
        acc2 = fmaf(aB, lo16f(vB.y), acc2); acc3 = fmaf(aB, hi16f(vB.y), acc3);
        acc0 = fmaf(aC, lo16f(vC.x), acc0); acc1 = fmaf(aC, hi16f(vC.x), acc1);
        acc2 = fmaf(aC, lo16f(vC.y), acc2); acc3 = fmaf(aC, hi16f(vC.y), acc3);
        acc0 = fmaf(aD, lo16f(vD.x), acc0); acc1 = fmaf(aD, hi16f(vD.x), acc1);
        acc2 = fmaf(aD, lo16f(vD.y), acc2); acc3 = fmaf(aD, hi16f(vD.y), acc3);
      }
    }
  }
  // reduce lane-private denom partials within each 16-lane head group (once)
  denp += __shfl_xor(denp, 1);
  denp += __shfl_xor(denp, 2);
  denp += __shfl_xor(denp, 4);
  denp += __shfl_xor(denp, 8);
  // combine the two half-wave partial sums (each holds one edge parity)
  acc0 += __shfl_xor(acc0, 32);
  acc1 += __shfl_xor(acc1, 32);
  acc2 += __shfl_xor(acc2, 32);
  acc3 += __shfl_xor(acc3, 32);
  float inv = 1.f / __shfl(denp, hg*16);
  if (half == 0){
    int cb = q*4;
    float4 o;
    o.x = acc0*inv + bias[cb];
    o.y = acc1*inv + bias[cb+1];
    o.z = acc2*inv + bias[cb+2];
    o.w = acc3*inv + bias[cb+3];
    ((float4*)(out + (size_t)n*D))[q] = o;
  }
}

// ---------------- BatchNorm stats ----------------
__global__ __launch_bounds__(256) void k_bnstat(const float* __restrict__ B,
                                                float* __restrict__ bsum, float* __restrict__ bsq){
  __shared__ float sS[256], sQ[256];
  int tid = threadIdx.x;
  int c = tid & 127;
  int rr = tid >> 7;
  int r0 = blockIdx.x * 64;
  int r1 = r0 + 64; if (r1 > NN) r1 = NN;
  float s = 0.f, qv = 0.f;
  for (int r = r0 + rr; r < r1; r += 2){
    float v = B[(size_t)r*D + c];
    s += v; qv += v*v;
  }
  sS[tid] = s; sQ[tid] = qv;
  __syncthreads();
  if (tid < 128){
    atomicAdd(&bsum[c], sS[tid] + sS[tid+128]);
    atomicAdd(&bsq[c],  sQ[tid] + sQ[tid+128]);
  }
}

// ---------------- global mean pool (batch sorted) ----------------
#define POOL_ROWS 50
__global__ void k_poolA(const float* __restrict__ h2, const int* __restrict__ batch,
                        float* __restrict__ pooled){
  int c = threadIdx.x & 127;
  int half = threadIdx.x >> 7;
  int r0 = blockIdx.x * POOL_ROWS;
  int r1 = r0 + POOL_ROWS; if (r1 > NN) r1 = NN;
  float s = 0.f; int g = -1;
  for (int r = r0 + half; r < r1; r += 2){
    int bg = batch[r];
    if (bg != g){
      if (g >= 0) atomicAdd(&pooled[g*D + c], s);
      g = bg; s = 0.f;
    }
    s += h2[(size_t)r*D + c];
  }
  if (g >= 0) atomicAdd(&pooled[g*D + c], s);
}

__global__ void k_poolB(const float* __restrict__ pooled, const int* __restrict__ batch,
                        float* __restrict__ out){
  int g = blockIdx.x;
  int c = threadIdx.x;   // 128
  int lo = 0, hi = NN;
  while (lo < hi){ int mid = (lo+hi) >> 1; if (batch[mid] < g) lo = mid+1; else hi = mid; }
  int a = lo, b = NN;
  while (a < b){ int mid = (a+b) >> 1; if (batch[mid] < g+1) a = mid+1; else b = mid; }
  int cntg = a - lo;
  out[g*D + c] = pooled[g*D + c] / (float)(cntg > 1 ? cntg : 1);
}

extern "C" void kernel_launch(void* const* d_in, const int* in_sizes, int n_in,
                              void* d_out, int out_size, void* d_ws, size_t ws_size,
                              hipStream_t stream){
  (void)in_sizes; (void)n_in; (void)out_size; (void)ws_size;
  const float* x   = (const float*)d_in[0];
  const int* ei    = (const int*)d_in[1];
  const int* batch = (const int*)d_in[2];
  const float* W1  = (const float*)d_in[3];
  const float* as1 = (const float*)d_in[4];
  const float* ad1 = (const float*)d_in[5];
  const float* b1  = (const float*)d_in[6];
  const float* g1  = (const float*)d_in[7];
  const float* be1 = (const float*)d_in[8];
  const float* W2  = (const float*)d_in[9];
  const float* as2 = (const float*)d_in[10];
  const float* ad2 = (const float*)d_in[11];
  const float* b2  = (const float*)d_in[12];
  float* outp = (float*)d_out;

  float* B    = (float*)d_ws;            // 6.4M f32
  float* asr  = B + 6400000;             // 200K
  float* ads  = asr + 200000;            // 200K
  float* bsum = ads + 200000;            // 128
  float* bsq  = bsum + 128;              // 128
  float* pooled = bsq + 128;             // 8192
  int* cnt    = (int*)(pooled + NG*D);   // 50000
  int* cur    = cnt + NN;                // 50000
  int* offs   = cur + NN;                // 50001
  int* srcs   = offs + (NN+1);           // 850000
  int* bsums  = srcs + ET;               // 256
  u16* hb     = (u16*)(bsums + 256);     // 6.4M bf16 (12.8 MB)

  const int* srcE = ei;
  const int* dstE = ei + NE;

  k_init<<<196, 256, 0, stream>>>(cnt, cur, bsum, bsq, pooled);
  // layer-1 GEMM (+att dots +edge histogram)
  k_gemm<0><<<782, 256, 0, stream>>>(x, W1, hb, as1, ad1, asr, ads,
                                     dstE, cnt, nullptr, nullptr, nullptr, nullptr, NN);
  k_scan_a<<<196, 256, 0, stream>>>(cnt, offs, bsums);
  k_scan_c2<<<196, 256, 0, stream>>>(offs, bsums);
  k_scatter<<<(ET+255)/256, 256, 0, stream>>>(srcE, dstE, offs, cur, srcs);
  k_edge<<<NN/4, 256, 0, stream>>>(hb, asr, ads, offs, srcs, b1, B);
  k_bnstat<<<782, 256, 0, stream>>>(B, bsum, bsq);
  // layer-2 GEMM with fused BN-finalize + BN+ELU on input (+att dots)
  k_gemm<1><<<782, 256, 0, stream>>>(B, W2, hb, as2, ad2, asr, ads,
                                     nullptr, nullptr, bsum, bsq, g1, be1, NN);
  k_edge<<<NN/4, 256, 0, stream>>>(hb, asr, ads, offs, srcs, b2, outp);
  k_poolA<<<(NN + POOL_ROWS - 1)/POOL_ROWS, 256, 0, stream>>>(outp, batch, pooled);
  k_poolB<<<NG, 128, 0, stream>>>(pooled, batch, outp + 6400000);
}